// Round 1
// baseline (547.360 us; speedup 1.0000x reference)
//
#include <hip/hip_runtime.h>

// ---------------------------------------------------------------------------
// AttnBlock: GroupNorm -> q,k,v 1x1 conv -> softmax(QK^T/sqrt(c)) V -> out
// conv -> residual.  b=4, c=512, h=w=64 (n=4096), 32 groups.
// All matmuls in bf16 MFMA (16x16x32), f32 accumulate.
// ---------------------------------------------------------------------------

typedef __attribute__((ext_vector_type(8))) short bf16x8;   // 8 bf16 (4 VGPR)
typedef __attribute__((ext_vector_type(4))) float f32x4;    // MFMA acc frag

#define MFMA16(a, b, c) __builtin_amdgcn_mfma_f32_16x16x32_bf16((a), (b), (c), 0, 0, 0)

#define B_   4
#define C_   512
#define N_   4096
#define G_   32
#define SCALE 0.044194173824159216f  // 1/sqrt(512)

__device__ __forceinline__ unsigned short f2bf(float f) {
    union { float f; unsigned int u; } v; v.f = f;
    unsigned int r = (v.u + 0x7fffu + ((v.u >> 16) & 1u)) >> 16;  // RNE
    return (unsigned short)r;
}
__device__ __forceinline__ float bf2f(unsigned short s) {
    union { unsigned int u; float f; } v; v.u = ((unsigned int)s) << 16;
    return v.f;
}

// ---------------- GroupNorm stats: one block per (b,g) ----------------------
__global__ __launch_bounds__(256) void gn_stats(const float* __restrict__ x,
                                                float* __restrict__ stats) {
    int blk = blockIdx.x;  // b*32 + g ; group = 16 channels * 4096 contiguous
    const float4* base = (const float4*)(x + (size_t)blk * 65536);
    float s = 0.f, ss = 0.f;
    for (int i = threadIdx.x; i < 16384; i += 256) {
        float4 v = base[i];
        s  += v.x + v.y + v.z + v.w;
        ss += v.x * v.x + v.y * v.y + v.z * v.z + v.w * v.w;
    }
    __shared__ float red[512];
    int t = threadIdx.x;
    red[t] = s; red[256 + t] = ss;
    __syncthreads();
    for (int st = 128; st > 0; st >>= 1) {
        if (t < st) { red[t] += red[t + st]; red[256 + t] += red[256 + t + st]; }
        __syncthreads();
    }
    if (t == 0) {
        float mean = red[0] * (1.f / 65536.f);
        float var  = red[256] * (1.f / 65536.f) - mean * mean;
        stats[blk] = mean;
        stats[128 + blk] = rsqrtf(var + 1e-6f);
    }
}

// ------------- GroupNorm apply + transpose -> Ht[b][n][c] bf16 --------------
__global__ __launch_bounds__(256) void gn_apply(const float* __restrict__ x,
                                                const float* __restrict__ gamma,
                                                const float* __restrict__ beta,
                                                const float* __restrict__ stats,
                                                unsigned short* __restrict__ ht) {
    __shared__ float tile[64][65];
    int j0 = blockIdx.x * 64, c0 = blockIdx.y * 64, b = blockIdx.z;
    int t = threadIdx.x;
#pragma unroll
    for (int i = 0; i < 16; ++i) {
        int lid = i * 256 + t;
        int cl = lid >> 6, jl = lid & 63;
        int c = c0 + cl, g = c >> 4;
        float mean = stats[b * 32 + g], rstd = stats[128 + b * 32 + g];
        float v = x[((size_t)b * C_ + c) * N_ + j0 + jl];
        tile[cl][jl] = (v - mean) * rstd * gamma[c] + beta[c];
    }
    __syncthreads();
#pragma unroll
    for (int i = 0; i < 16; ++i) {
        int lid = i * 256 + t;
        int jl = lid >> 6, cl = lid & 63;
        ht[((size_t)b * N_ + j0 + jl) * C_ + c0 + cl] = f2bf(tile[cl][jl]);
    }
}

// ------------- convert the 4 weight matrices to bf16 ------------------------
__global__ __launch_bounds__(256) void wconv(const float* __restrict__ wq,
                                             const float* __restrict__ wk,
                                             const float* __restrict__ wv,
                                             const float* __restrict__ wo,
                                             unsigned short* __restrict__ dst) {
    size_t i = (size_t)blockIdx.x * 256 + threadIdx.x;  // 4*512*512 total
    int m = (int)(i >> 18);
    size_t off = i & 262143;
    const float* src = (m == 0) ? wq : (m == 1) ? wk : (m == 2) ? wv : wo;
    dst[i] = f2bf(src[off]);
}

// ------------- 128x128x(K=512) bf16 GEMM, two orientations ------------------
// hsrc: [b][4096][512] bf16 (Ht or attn-out), wsrc: [512][512] bf16.
// MODE 0: out[b][j][co] = sum_ci hsrc[j][ci]*wsrc[co][ci] + bias[co]  (bf16)
// MODE 1: out[b][co][j] = same + bias[co]                              (bf16)
// MODE 2: outf[b][co][j] = same + bias[co] + xres[b][co][j]            (f32)
template <int MODE>
__global__ __launch_bounds__(256) void gemm128(const unsigned short* __restrict__ hsrc,
                                               const unsigned short* __restrict__ wsrc,
                                               const float* __restrict__ bias,
                                               unsigned short* __restrict__ outb,
                                               float* __restrict__ outf,
                                               const float* __restrict__ xres) {
    __shared__ unsigned short hl[128 * 72];  // +8 pad: 2-way banks (free)
    __shared__ unsigned short wl[128 * 72];
    int b = blockIdx.z;
    int j0 = blockIdx.x * 128, co0 = blockIdx.y * 128;
    int t = threadIdx.x;
    int w = t >> 6, lane = t & 63, l15 = lane & 15, quad = lane >> 4;
    int wm = w & 1, wn = w >> 1;
    f32x4 acc[4][4] = {};
    for (int k0 = 0; k0 < 512; k0 += 64) {
        __syncthreads();
#pragma unroll
        for (int i = 0; i < 4; ++i) {
            int idx = i * 256 + t;
            int row = idx >> 3, u = idx & 7;
            *(uint4*)&hl[row * 72 + u * 8] =
                *(const uint4*)&hsrc[((size_t)b * N_ + j0 + row) * C_ + k0 + u * 8];
            *(uint4*)&wl[row * 72 + u * 8] =
                *(const uint4*)&wsrc[(size_t)(co0 + row) * C_ + k0 + u * 8];
        }
        __syncthreads();
#pragma unroll
        for (int kk = 0; kk < 2; ++kk) {
            const unsigned short* ab = (MODE == 0) ? hl : wl;  // A covers m-side
            const unsigned short* bb = (MODE == 0) ? wl : hl;  // B covers n-side
            bf16x8 af[4], bfr[4];
#pragma unroll
            for (int mi = 0; mi < 4; ++mi)
                af[mi] = *(const bf16x8*)&ab[(wm * 64 + mi * 16 + l15) * 72 + kk * 32 + quad * 8];
#pragma unroll
            for (int ni = 0; ni < 4; ++ni)
                bfr[ni] = *(const bf16x8*)&bb[(wn * 64 + ni * 16 + l15) * 72 + kk * 32 + quad * 8];
#pragma unroll
            for (int mi = 0; mi < 4; ++mi)
#pragma unroll
                for (int ni = 0; ni < 4; ++ni)
                    acc[mi][ni] = MFMA16(af[mi], bfr[ni], acc[mi][ni]);
        }
    }
#pragma unroll
    for (int mi = 0; mi < 4; ++mi)
#pragma unroll
        for (int ni = 0; ni < 4; ++ni)
#pragma unroll
            for (int r = 0; r < 4; ++r) {
                int mrow = wm * 64 + mi * 16 + quad * 4 + r;
                int ncol = wn * 64 + ni * 16 + l15;
                float v = acc[mi][ni][r];
                if (MODE == 0) {
                    int j = j0 + mrow, co = co0 + ncol;
                    outb[((size_t)b * N_ + j) * C_ + co] = f2bf(v + bias[co]);
                } else {
                    int co = co0 + mrow, j = j0 + ncol;
                    size_t o = ((size_t)b * C_ + co) * N_ + j;
                    if (MODE == 1) outb[o] = f2bf(v + bias[co]);
                    else           outf[o] = v + bias[co] + xres[o];
                }
            }
}

// ------------- flash attention: 128 q-rows/block, Bc=32, split-K ------------
// Qt,Kt: [b][n][c] bf16.  Vg: [b][c][n] bf16.
// part: [split][b][n][c] bf16 unnormalized O~;  mbuf/lbuf: [split][b][n] f32.
__global__ __launch_bounds__(512) void flash_attn(const unsigned short* __restrict__ Qt,
                                                  const unsigned short* __restrict__ Kt,
                                                  const unsigned short* __restrict__ Vg,
                                                  unsigned short* __restrict__ part,
                                                  float* __restrict__ mbuf,
                                                  float* __restrict__ lbuf,
                                                  int nsplit) {
    __shared__ unsigned short Klds[32 * 520];   // [kcol][c], +8 pad
    __shared__ unsigned short Vh[256 * 40];     // half of V cols: [co][k], +8 pad
    __shared__ unsigned short Plds[8 * 16 * 40];  // per-wave P: [16 q][32 k], +8 pad
    int q0 = blockIdx.x * 128, b = blockIdx.y, s = blockIdx.z;
    int t = threadIdx.x, w = t >> 6, lane = t & 63, l15 = lane & 15, quad = lane >> 4;
    int klen = N_ / nsplit, kbeg = s * klen, nkt = klen / 32;

    // Q fragments for this wave's 16 rows: A[m=l15][k=quad*8+j], 16 chunks of 32.
    bf16x8 qa[16];
    const unsigned short* qb = Qt + ((size_t)b * N_ + q0 + w * 16 + l15) * C_ + quad * 8;
#pragma unroll
    for (int ck = 0; ck < 16; ++ck) qa[ck] = *(const bf16x8*)(qb + ck * 32);

    f32x4 o[32] = {};
    float mrow[4], lrow[4];
#pragma unroll
    for (int r = 0; r < 4; ++r) { mrow[r] = -1e30f; lrow[r] = 0.f; }

    for (int kt = 0; kt < nkt; ++kt) {
        int k0 = kbeg + kt * 32;
        __syncthreads();  // prior-iter consumers done
        {   // stage K tile [32][512] and V half0 [co 0..255][32]
            const unsigned short* kb = Kt + ((size_t)b * N_ + k0) * C_;
#pragma unroll
            for (int i = 0; i < 4; ++i) {
                int idx = i * 512 + t; int row = idx >> 6, u = idx & 63;
                *(uint4*)&Klds[row * 520 + u * 8] = *(const uint4*)&kb[(size_t)row * C_ + u * 8];
            }
            const unsigned short* vb = Vg + (size_t)b * C_ * N_ + k0;
#pragma unroll
            for (int i = 0; i < 2; ++i) {
                int idx = i * 512 + t; int row = idx >> 2, u = idx & 3;
                *(uint4*)&Vh[row * 40 + u * 8] = *(const uint4*)&vb[(size_t)row * N_ + u * 8];
            }
        }
        __syncthreads();
        // ---- S = Q K^T  (two 16-col fragments) ----
        f32x4 s0 = {}, s1 = {};
#pragma unroll
        for (int ck = 0; ck < 16; ++ck) {
            bf16x8 b0 = *(const bf16x8*)&Klds[l15 * 520 + ck * 32 + quad * 8];
            bf16x8 b1 = *(const bf16x8*)&Klds[(16 + l15) * 520 + ck * 32 + quad * 8];
            s0 = MFMA16(qa[ck], b0, s0);
            s1 = MFMA16(qa[ck], b1, s1);
        }
        // ---- online softmax (rows = quad*4+r; cols reduced over l15) ----
        float alpha[4];
        unsigned short* pb = &Plds[w * 640];
#pragma unroll
        for (int r = 0; r < 4; ++r) {
            float v0 = s0[r] * SCALE, v1 = s1[r] * SCALE;
            float mx = fmaxf(v0, v1);
            mx = fmaxf(mx, __shfl_xor(mx, 1));
            mx = fmaxf(mx, __shfl_xor(mx, 2));
            mx = fmaxf(mx, __shfl_xor(mx, 4));
            mx = fmaxf(mx, __shfl_xor(mx, 8));
            float mnew = fmaxf(mrow[r], mx);
            alpha[r] = __expf(mrow[r] - mnew);
            mrow[r] = mnew;
            float p0 = __expf(v0 - mnew), p1 = __expf(v1 - mnew);
            float rs = p0 + p1;
            rs += __shfl_xor(rs, 1);
            rs += __shfl_xor(rs, 2);
            rs += __shfl_xor(rs, 4);
            rs += __shfl_xor(rs, 8);
            lrow[r] = lrow[r] * alpha[r] + rs;
            pb[(quad * 4 + r) * 40 + l15]      = f2bf(p0);
            pb[(quad * 4 + r) * 40 + 16 + l15] = f2bf(p1);
        }
#pragma unroll
        for (int cf = 0; cf < 32; ++cf) {
            o[cf][0] *= alpha[0]; o[cf][1] *= alpha[1];
            o[cf][2] *= alpha[2]; o[cf][3] *= alpha[3];
        }
        // ---- P V : A-frag from own-wave Plds, B-frags from Vh ----
        bf16x8 pa = *(const bf16x8*)&Plds[w * 640 + l15 * 40 + quad * 8];
#pragma unroll
        for (int cf = 0; cf < 16; ++cf) {
            bf16x8 vb = *(const bf16x8*)&Vh[(cf * 16 + l15) * 40 + quad * 8];
            o[cf] = MFMA16(pa, vb, o[cf]);
        }
        __syncthreads();  // everyone done with Vh half0
        {   // stage V half1 [co 256..511]
            const unsigned short* vb2 = Vg + ((size_t)b * C_ + 256) * N_ + k0;
#pragma unroll
            for (int i = 0; i < 2; ++i) {
                int idx = i * 512 + t; int row = idx >> 2, u = idx & 3;
                *(uint4*)&Vh[row * 40 + u * 8] = *(const uint4*)&vb2[(size_t)row * N_ + u * 8];
            }
        }
        __syncthreads();
#pragma unroll
        for (int cf = 0; cf < 16; ++cf) {
            bf16x8 vb = *(const bf16x8*)&Vh[(cf * 16 + l15) * 40 + quad * 8];
            o[16 + cf] = MFMA16(pa, vb, o[16 + cf]);
        }
    }
    // ---- write unnormalized partial + (m,l) ----
    size_t pbase = (size_t)(s * B_ + b) * N_;
#pragma unroll
    for (int cf = 0; cf < 32; ++cf)
#pragma unroll
        for (int r = 0; r < 4; ++r) {
            int q = q0 + w * 16 + quad * 4 + r;
            part[(pbase + q) * C_ + cf * 16 + l15] = f2bf(o[cf][r]);
        }
    if (l15 == 0) {
#pragma unroll
        for (int r = 0; r < 4; ++r) {
            int q = q0 + w * 16 + quad * 4 + r;
            mbuf[pbase + q] = mrow[r];
            lbuf[pbase + q] = lrow[r];
        }
    }
}

// ------------- combine split-K partials -> AObf[b][n][c] bf16 ---------------
__global__ __launch_bounds__(256) void attn_combine(const unsigned short* __restrict__ part,
                                                    const float* __restrict__ mbuf,
                                                    const float* __restrict__ lbuf,
                                                    unsigned short* __restrict__ ao,
                                                    int nsplit) {
    size_t idx = (size_t)blockIdx.x * 256 + threadIdx.x;  // 16384*64 threads
    int cu = (int)(idx & 63);
    size_t row = idx >> 6;  // b*4096 + q
    float m1 = mbuf[row], l1 = lbuf[row];
    union { uint4 v; unsigned short u[8]; } p1, p2, outv;
    p1.v = *(const uint4*)&part[row * C_ + cu * 8];
    float a1 = 1.f, a2 = 0.f, inv;
    if (nsplit == 2) {
        float m2 = mbuf[(size_t)B_ * N_ + row], l2 = lbuf[(size_t)B_ * N_ + row];
        p2.v = *(const uint4*)&part[((size_t)B_ * N_ + row) * C_ + cu * 8];
        float mm = fmaxf(m1, m2);
        a1 = __expf(m1 - mm);
        a2 = __expf(m2 - mm);
        inv = 1.f / (a1 * l1 + a2 * l2);
    } else {
        inv = 1.f / l1;
        p2.v = p1.v;  // unused (a2=0)
    }
#pragma unroll
    for (int j = 0; j < 8; ++j)
        outv.u[j] = f2bf((bf2f(p1.u[j]) * a1 + bf2f(p2.u[j]) * a2) * inv);
    *(uint4*)&ao[row * C_ + cu * 8] = outv.v;
}

// ---------------------------------------------------------------------------
extern "C" void kernel_launch(void* const* d_in, const int* in_sizes, int n_in,
                              void* d_out, int out_size, void* d_ws, size_t ws_size,
                              hipStream_t stream) {
    const float* x   = (const float*)d_in[0];
    const float* gam = (const float*)d_in[1];
    const float* bet = (const float*)d_in[2];
    const float* wq  = (const float*)d_in[3];
    const float* bq  = (const float*)d_in[4];
    const float* wk  = (const float*)d_in[5];
    const float* bk  = (const float*)d_in[6];
    const float* wv  = (const float*)d_in[7];
    const float* bv  = (const float*)d_in[8];
    const float* wo  = (const float*)d_in[9];
    const float* bo  = (const float*)d_in[10];
    float* out = (float*)d_out;

    char* ws = (char*)d_ws;
    const size_t SZH = (size_t)B_ * N_ * C_ * 2;  // 16 MiB bf16 tensor
    float*          stats = (float*)ws;                                   // 4 KiB
    unsigned short* Ht    = (unsigned short*)(ws + 4096);
    unsigned short* Qt    = (unsigned short*)(ws + 4096 + SZH);
    unsigned short* Kt    = (unsigned short*)(ws + 4096 + 2 * SZH);
    unsigned short* Vg    = (unsigned short*)(ws + 4096 + 3 * SZH);
    unsigned short* Wb    = (unsigned short*)(ws + 4096 + 4 * SZH);       // 2 MiB
    float*          mbuf  = (float*)(ws + 4096 + 4 * SZH + 2097152);      // 128 KiB
    float*          lbuf  = (float*)(ws + 4096 + 4 * SZH + 2097152 + 131072);
    unsigned short* part  = (unsigned short*)(ws + 4096 + 4 * SZH + 2097152 + 262144);
    size_t need2 = 4096 + 4 * SZH + 2097152 + 262144 + 2 * SZH;
    int nsplit = (ws_size >= need2) ? 2 : 1;  // deterministic per run
    unsigned short* AObf = Ht;  // Ht dead after projections; reuse for attn out

    gn_stats<<<128, 256, 0, stream>>>(x, stats);
    gn_apply<<<dim3(64, 8, B_), 256, 0, stream>>>(x, gam, bet, stats, Ht);
    wconv<<<4096, 256, 0, stream>>>(wq, wk, wv, wo, Wb);
    gemm128<0><<<dim3(32, 4, B_), 256, 0, stream>>>(Ht, Wb,          bq, Qt, nullptr, nullptr);
    gemm128<0><<<dim3(32, 4, B_), 256, 0, stream>>>(Ht, Wb + 262144, bk, Kt, nullptr, nullptr);
    gemm128<1><<<dim3(32, 4, B_), 256, 0, stream>>>(Ht, Wb + 524288, bv, Vg, nullptr, nullptr);
    flash_attn<<<dim3(32, B_, nsplit), 512, 0, stream>>>(Qt, Kt, Vg, part, mbuf, lbuf, nsplit);
    attn_combine<<<4096, 256, 0, stream>>>(part, mbuf, lbuf, AObf, nsplit);
    gemm128<2><<<dim3(32, 4, B_), 256, 0, stream>>>(AObf, Wb + 786432, bo, nullptr, out, x);
}

// Round 2
// 526.927 us; speedup vs baseline: 1.0388x; 1.0388x over previous
//
#include <hip/hip_runtime.h>

// ---------------------------------------------------------------------------
// AttnBlock: GroupNorm -> q,k,v 1x1 conv -> softmax(QK^T/sqrt(c)) V -> out
// conv -> residual.  b=4, c=512, h=w=64 (n=4096), 32 groups.
// All matmuls in bf16 MFMA (16x16x32), f32 accumulate.
// R1: flash_attn rebuilt around async global_load_lds + LDS double-buffer
//     (1 barrier/iter instead of 4), XOR-swizzled K LDS (no padding allowed
//     with global_load_lds), [kc][co] V layout, ballot-gated rescale.
// ---------------------------------------------------------------------------

typedef __attribute__((ext_vector_type(8))) short bf16x8;   // 8 bf16 (4 VGPR)
typedef __attribute__((ext_vector_type(4))) float f32x4;    // MFMA acc frag

#define MFMA16(a, b, c) __builtin_amdgcn_mfma_f32_16x16x32_bf16((a), (b), (c), 0, 0, 0)

#define B_   4
#define C_   512
#define N_   4096
#define G_   32
#define SCALE 0.044194173824159216f  // 1/sqrt(512)

__device__ __forceinline__ unsigned short f2bf(float f) {
    union { float f; unsigned int u; } v; v.f = f;
    unsigned int r = (v.u + 0x7fffu + ((v.u >> 16) & 1u)) >> 16;  // RNE
    return (unsigned short)r;
}
__device__ __forceinline__ float bf2f(unsigned short s) {
    union { unsigned int u; float f; } v; v.u = ((unsigned int)s) << 16;
    return v.f;
}

// async 16B global -> LDS (lane i lands at lds + i*16)
__device__ __forceinline__ void async16(const unsigned short* g, unsigned short* l) {
    __builtin_amdgcn_global_load_lds((const __attribute__((address_space(1))) unsigned int*)g,
                                     (__attribute__((address_space(3))) unsigned int*)l,
                                     16, 0, 0);
}

// ---------------- GroupNorm stats: one block per (b,g) ----------------------
__global__ __launch_bounds__(256) void gn_stats(const float* __restrict__ x,
                                                float* __restrict__ stats) {
    int blk = blockIdx.x;  // b*32 + g ; group = 16 channels * 4096 contiguous
    const float4* base = (const float4*)(x + (size_t)blk * 65536);
    float s = 0.f, ss = 0.f;
    for (int i = threadIdx.x; i < 16384; i += 256) {
        float4 v = base[i];
        s  += v.x + v.y + v.z + v.w;
        ss += v.x * v.x + v.y * v.y + v.z * v.z + v.w * v.w;
    }
    __shared__ float red[512];
    int t = threadIdx.x;
    red[t] = s; red[256 + t] = ss;
    __syncthreads();
    for (int st = 128; st > 0; st >>= 1) {
        if (t < st) { red[t] += red[t + st]; red[256 + t] += red[256 + t + st]; }
        __syncthreads();
    }
    if (t == 0) {
        float mean = red[0] * (1.f / 65536.f);
        float var  = red[256] * (1.f / 65536.f) - mean * mean;
        stats[blk] = mean;
        stats[128 + blk] = rsqrtf(var + 1e-6f);
    }
}

// ------------- GroupNorm apply + transpose -> Ht[b][n][c] bf16 --------------
__global__ __launch_bounds__(256) void gn_apply(const float* __restrict__ x,
                                                const float* __restrict__ gamma,
                                                const float* __restrict__ beta,
                                                const float* __restrict__ stats,
                                                unsigned short* __restrict__ ht) {
    __shared__ float tile[64][65];
    int j0 = blockIdx.x * 64, c0 = blockIdx.y * 64, b = blockIdx.z;
    int t = threadIdx.x;
#pragma unroll
    for (int i = 0; i < 16; ++i) {
        int lid = i * 256 + t;
        int cl = lid >> 6, jl = lid & 63;
        int c = c0 + cl, g = c >> 4;
        float mean = stats[b * 32 + g], rstd = stats[128 + b * 32 + g];
        float v = x[((size_t)b * C_ + c) * N_ + j0 + jl];
        tile[cl][jl] = (v - mean) * rstd * gamma[c] + beta[c];
    }
    __syncthreads();
#pragma unroll
    for (int i = 0; i < 16; ++i) {
        int lid = i * 256 + t;
        int jl = lid >> 6, cl = lid & 63;
        ht[((size_t)b * N_ + j0 + jl) * C_ + c0 + cl] = f2bf(tile[cl][jl]);
    }
}

// ------------- convert the 4 weight matrices to bf16 ------------------------
__global__ __launch_bounds__(256) void wconv(const float* __restrict__ wq,
                                             const float* __restrict__ wk,
                                             const float* __restrict__ wv,
                                             const float* __restrict__ wo,
                                             unsigned short* __restrict__ dst) {
    size_t i = (size_t)blockIdx.x * 256 + threadIdx.x;  // 4*512*512 total
    int m = (int)(i >> 18);
    size_t off = i & 262143;
    const float* src = (m == 0) ? wq : (m == 1) ? wk : (m == 2) ? wv : wo;
    dst[i] = f2bf(src[off]);
}

// ------------- 128x128x(K=512) bf16 GEMM, two orientations ------------------
template <int MODE>
__global__ __launch_bounds__(256) void gemm128(const unsigned short* __restrict__ hsrc,
                                               const unsigned short* __restrict__ wsrc,
                                               const float* __restrict__ bias,
                                               unsigned short* __restrict__ outb,
                                               float* __restrict__ outf,
                                               const float* __restrict__ xres) {
    __shared__ unsigned short hl[128 * 72];
    __shared__ unsigned short wl[128 * 72];
    int b = blockIdx.z;
    int j0 = blockIdx.x * 128, co0 = blockIdx.y * 128;
    int t = threadIdx.x;
    int w = t >> 6, lane = t & 63, l15 = lane & 15, quad = lane >> 4;
    int wm = w & 1, wn = w >> 1;
    f32x4 acc[4][4] = {};
    for (int k0 = 0; k0 < 512; k0 += 64) {
        __syncthreads();
#pragma unroll
        for (int i = 0; i < 4; ++i) {
            int idx = i * 256 + t;
            int row = idx >> 3, u = idx & 7;
            *(uint4*)&hl[row * 72 + u * 8] =
                *(const uint4*)&hsrc[((size_t)b * N_ + j0 + row) * C_ + k0 + u * 8];
            *(uint4*)&wl[row * 72 + u * 8] =
                *(const uint4*)&wsrc[(size_t)(co0 + row) * C_ + k0 + u * 8];
        }
        __syncthreads();
#pragma unroll
        for (int kk = 0; kk < 2; ++kk) {
            const unsigned short* ab = (MODE == 0) ? hl : wl;
            const unsigned short* bb = (MODE == 0) ? wl : hl;
            bf16x8 af[4], bfr[4];
#pragma unroll
            for (int mi = 0; mi < 4; ++mi)
                af[mi] = *(const bf16x8*)&ab[(wm * 64 + mi * 16 + l15) * 72 + kk * 32 + quad * 8];
#pragma unroll
            for (int ni = 0; ni < 4; ++ni)
                bfr[ni] = *(const bf16x8*)&bb[(wn * 64 + ni * 16 + l15) * 72 + kk * 32 + quad * 8];
#pragma unroll
            for (int mi = 0; mi < 4; ++mi)
#pragma unroll
                for (int ni = 0; ni < 4; ++ni)
                    acc[mi][ni] = MFMA16(af[mi], bfr[ni], acc[mi][ni]);
        }
    }
#pragma unroll
    for (int mi = 0; mi < 4; ++mi)
#pragma unroll
        for (int ni = 0; ni < 4; ++ni)
#pragma unroll
            for (int r = 0; r < 4; ++r) {
                int mrow = wm * 64 + mi * 16 + quad * 4 + r;
                int ncol = wn * 64 + ni * 16 + l15;
                float v = acc[mi][ni][r];
                if (MODE == 0) {
                    int j = j0 + mrow, co = co0 + ncol;
                    outb[((size_t)b * N_ + j) * C_ + co] = f2bf(v + bias[co]);
                } else {
                    int co = co0 + mrow, j = j0 + ncol;
                    size_t o = ((size_t)b * C_ + co) * N_ + j;
                    if (MODE == 1) outb[o] = f2bf(v + bias[co]);
                    else           outf[o] = v + bias[co] + xres[o];
                }
            }
}

// ------------- flash attention: async dbuf version --------------------------
// Qt,Kt: [b][n][c] bf16.  Vg: [b][c][n] bf16.
// Dynamic LDS (140,288 B):
//   Kl: 2 bufs x 32 rows x 512 shorts, chunk c of row r at slot c^(r&7)
//   Vl: 2 bufs x [kc 0..3][co 0..511] chunks of 8 shorts
//   Pl: 8 waves x 16 x 36 shorts
__global__ __launch_bounds__(512) void flash_attn(const unsigned short* __restrict__ Qt,
                                                  const unsigned short* __restrict__ Kt,
                                                  const unsigned short* __restrict__ Vg,
                                                  unsigned short* __restrict__ part,
                                                  float* __restrict__ mbuf,
                                                  float* __restrict__ lbuf,
                                                  int nsplit) {
    extern __shared__ unsigned short smem[];
    unsigned short* Kl = smem;            // 2 x 16384 shorts
    unsigned short* Vl = smem + 32768;    // 2 x 16384 shorts
    unsigned short* Pl = smem + 65536;    // 8 x 576 shorts

    int q0 = blockIdx.x * 128, b = blockIdx.y, s = blockIdx.z;
    int t = threadIdx.x, w = t >> 6, lane = t & 63, l15 = lane & 15, quad = lane >> 4;
    int klen = N_ / nsplit, kbeg = s * klen, nkt = klen / 32;
    int xr = l15 & 7;

    const unsigned short* Kbase = Kt + (size_t)b * N_ * C_;
    const unsigned short* Vbase = Vg + (size_t)b * C_ * N_;

    // Q fragments: 16 q rows per wave, A[m=l15][k=quad*8+j], 16 chunks of 32.
    bf16x8 qa[16];
    const unsigned short* qb = Qt + ((size_t)b * N_ + q0 + w * 16 + l15) * C_ + quad * 8;
#pragma unroll
    for (int ck = 0; ck < 16; ++ck) qa[ck] = *(const bf16x8*)(qb + ck * 32);

    f32x4 o[32] = {};
    float mrow[4], lrow[4];
#pragma unroll
    for (int r = 0; r < 4; ++r) { mrow[r] = -1e30f; lrow[r] = 0.f; }

    // ---- stage tile 0 into buf 0 (4 K rows + 4 V instrs per wave) ----
    {
        int k0 = kbeg;
#pragma unroll
        for (int i = 0; i < 4; ++i) {
            int r = w * 4 + i;
            async16(Kbase + (size_t)(k0 + r) * C_ + ((lane ^ (r & 7)) * 8),
                    Kl + r * 512);
        }
#pragma unroll
        for (int i = 0; i < 4; ++i) {
            int idx = w * 4 + i, kc = idx >> 3, cb = idx & 7;
            async16(Vbase + (size_t)(cb * 64 + lane) * N_ + k0 + kc * 8,
                    Vl + (kc * 512 + cb * 64) * 8);
        }
    }

    for (int kt = 0; kt < nkt; ++kt) {
        int cur = kt & 1, nxt = cur ^ 1;
        __builtin_amdgcn_s_waitcnt(0x3F70);   // vmcnt(0): drain buf[cur] staging
        __syncthreads();
        if (kt + 1 < nkt) {                   // issue next tile, no wait
            int k0 = kbeg + (kt + 1) * 32;
#pragma unroll
            for (int i = 0; i < 4; ++i) {
                int r = w * 4 + i;
                async16(Kbase + (size_t)(k0 + r) * C_ + ((lane ^ (r & 7)) * 8),
                        Kl + nxt * 16384 + r * 512);
            }
#pragma unroll
            for (int i = 0; i < 4; ++i) {
                int idx = w * 4 + i, kc = idx >> 3, cb = idx & 7;
                async16(Vbase + (size_t)(cb * 64 + lane) * N_ + k0 + kc * 8,
                        Vl + nxt * 16384 + (kc * 512 + cb * 64) * 8);
            }
        }
        // ---- S = Q K^T over buf[cur] ----
        const unsigned short* Kc = Kl + cur * 16384;
        f32x4 s0 = {}, s1 = {};
#pragma unroll
        for (int ck = 0; ck < 16; ++ck) {
            int slot = (ck * 4 + quad) ^ xr;
            bf16x8 b0 = *(const bf16x8*)&Kc[l15 * 512 + slot * 8];
            bf16x8 b1 = *(const bf16x8*)&Kc[(16 + l15) * 512 + slot * 8];
            s0 = MFMA16(qa[ck], b0, s0);
            s1 = MFMA16(qa[ck], b1, s1);
        }
        // ---- online softmax ----
        float alpha[4];
        bool upd = false;
        unsigned short* pb = &Pl[w * 576];
#pragma unroll
        for (int r = 0; r < 4; ++r) {
            float v0 = s0[r] * SCALE, v1 = s1[r] * SCALE;
            float mx = fmaxf(v0, v1);
            mx = fmaxf(mx, __shfl_xor(mx, 1));
            mx = fmaxf(mx, __shfl_xor(mx, 2));
            mx = fmaxf(mx, __shfl_xor(mx, 4));
            mx = fmaxf(mx, __shfl_xor(mx, 8));
            float mnew = fmaxf(mrow[r], mx);
            upd = upd || (mnew > mrow[r]);
            alpha[r] = __expf(mrow[r] - mnew);
            mrow[r] = mnew;
            float p0 = __expf(v0 - mnew), p1 = __expf(v1 - mnew);
            float rs = p0 + p1;
            rs += __shfl_xor(rs, 1);
            rs += __shfl_xor(rs, 2);
            rs += __shfl_xor(rs, 4);
            rs += __shfl_xor(rs, 8);
            lrow[r] = lrow[r] * alpha[r] + rs;
            pb[(quad * 4 + r) * 36 + l15]      = f2bf(p0);
            pb[(quad * 4 + r) * 36 + 16 + l15] = f2bf(p1);
        }
        if (__ballot(upd)) {                 // wave-uniform rescale skip
#pragma unroll
            for (int cf = 0; cf < 32; ++cf) {
                o[cf][0] *= alpha[0]; o[cf][1] *= alpha[1];
                o[cf][2] *= alpha[2]; o[cf][3] *= alpha[3];
            }
        }
        __builtin_amdgcn_s_waitcnt(0xC07F);  // lgkmcnt(0): P writes visible to own wave
        // ---- P V over buf[cur] ----
        bf16x8 pa = *(const bf16x8*)&Pl[w * 576 + l15 * 36 + quad * 8];
        const unsigned short* Vc = Vl + cur * 16384;
#pragma unroll
        for (int cf = 0; cf < 32; ++cf) {
            bf16x8 vb = *(const bf16x8*)&Vc[(quad * 512 + cf * 16 + l15) * 8];
            o[cf] = MFMA16(pa, vb, o[cf]);
        }
    }
    // ---- write unnormalized partial + (m,l) ----
    size_t pbase = (size_t)(s * B_ + b) * N_;
#pragma unroll
    for (int cf = 0; cf < 32; ++cf)
#pragma unroll
        for (int r = 0; r < 4; ++r) {
            int q = q0 + w * 16 + quad * 4 + r;
            part[(pbase + q) * C_ + cf * 16 + l15] = f2bf(o[cf][r]);
        }
    if (l15 == 0) {
#pragma unroll
        for (int r = 0; r < 4; ++r) {
            int q = q0 + w * 16 + quad * 4 + r;
            mbuf[pbase + q] = mrow[r];
            lbuf[pbase + q] = lrow[r];
        }
    }
}

// ------------- combine split-K partials -> AObf[b][n][c] bf16 ---------------
__global__ __launch_bounds__(256) void attn_combine(const unsigned short* __restrict__ part,
                                                    const float* __restrict__ mbuf,
                                                    const float* __restrict__ lbuf,
                                                    unsigned short* __restrict__ ao,
                                                    int nsplit) {
    size_t idx = (size_t)blockIdx.x * 256 + threadIdx.x;
    int cu = (int)(idx & 63);
    size_t row = idx >> 6;  // b*4096 + q
    float m1 = mbuf[row], l1 = lbuf[row];
    union { uint4 v; unsigned short u[8]; } p1, p2, outv;
    p1.v = *(const uint4*)&part[row * C_ + cu * 8];
    float a1 = 1.f, a2 = 0.f, inv;
    if (nsplit == 2) {
        float m2 = mbuf[(size_t)B_ * N_ + row], l2 = lbuf[(size_t)B_ * N_ + row];
        p2.v = *(const uint4*)&part[((size_t)B_ * N_ + row) * C_ + cu * 8];
        float mm = fmaxf(m1, m2);
        a1 = __expf(m1 - mm);
        a2 = __expf(m2 - mm);
        inv = 1.f / (a1 * l1 + a2 * l2);
    } else {
        inv = 1.f / l1;
        p2.v = p1.v;
    }
#pragma unroll
    for (int j = 0; j < 8; ++j)
        outv.u[j] = f2bf((bf2f(p1.u[j]) * a1 + bf2f(p2.u[j]) * a2) * inv);
    *(uint4*)&ao[row * C_ + cu * 8] = outv.v;
}

// ---------------------------------------------------------------------------
extern "C" void kernel_launch(void* const* d_in, const int* in_sizes, int n_in,
                              void* d_out, int out_size, void* d_ws, size_t ws_size,
                              hipStream_t stream) {
    const float* x   = (const float*)d_in[0];
    const float* gam = (const float*)d_in[1];
    const float* bet = (const float*)d_in[2];
    const float* wq  = (const float*)d_in[3];
    const float* bq  = (const float*)d_in[4];
    const float* wk  = (const float*)d_in[5];
    const float* bk  = (const float*)d_in[6];
    const float* wv  = (const float*)d_in[7];
    const float* bv  = (const float*)d_in[8];
    const float* wo  = (const float*)d_in[9];
    const float* bo  = (const float*)d_in[10];
    float* out = (float*)d_out;

    char* ws = (char*)d_ws;
    const size_t SZH = (size_t)B_ * N_ * C_ * 2;  // 16 MiB bf16 tensor
    float*          stats = (float*)ws;
    unsigned short* Ht    = (unsigned short*)(ws + 4096);
    unsigned short* Qt    = (unsigned short*)(ws + 4096 + SZH);
    unsigned short* Kt    = (unsigned short*)(ws + 4096 + 2 * SZH);
    unsigned short* Vg    = (unsigned short*)(ws + 4096 + 3 * SZH);
    unsigned short* Wb    = (unsigned short*)(ws + 4096 + 4 * SZH);
    float*          mbuf  = (float*)(ws + 4096 + 4 * SZH + 2097152);
    float*          lbuf  = (float*)(ws + 4096 + 4 * SZH + 2097152 + 131072);
    unsigned short* part  = (unsigned short*)(ws + 4096 + 4 * SZH + 2097152 + 262144);
    size_t need2 = 4096 + 4 * SZH + 2097152 + 262144 + 2 * SZH;
    int nsplit = (ws_size >= need2) ? 2 : 1;  // deterministic per run
    unsigned short* AObf = Ht;

    const int FLASH_LDS = 140288;  // 2x32KB K + 2x32KB V + 9KB P
    (void)hipFuncSetAttribute((const void*)flash_attn,
                              hipFuncAttributeMaxDynamicSharedMemorySize, FLASH_LDS);

    gn_stats<<<128, 256, 0, stream>>>(x, stats);
    gn_apply<<<dim3(64, 8, B_), 256, 0, stream>>>(x, gam, bet, stats, Ht);
    wconv<<<4096, 256, 0, stream>>>(wq, wk, wv, wo, Wb);
    gemm128<0><<<dim3(32, 4, B_), 256, 0, stream>>>(Ht, Wb,          bq, Qt, nullptr, nullptr);
    gemm128<0><<<dim3(32, 4, B_), 256, 0, stream>>>(Ht, Wb + 262144, bk, Kt, nullptr, nullptr);
    gemm128<1><<<dim3(32, 4, B_), 256, 0, stream>>>(Ht, Wb + 524288, bv, Vg, nullptr, nullptr);
    flash_attn<<<dim3(32, B_, nsplit), 512, FLASH_LDS, stream>>>(Qt, Kt, Vg, part, mbuf, lbuf, nsplit);
    attn_combine<<<4096, 256, 0, stream>>>(part, mbuf, lbuf, AObf, nsplit);
    gemm128<2><<<dim3(32, 4, B_), 256, 0, stream>>>(AObf, Wb + 786432, bo, nullptr, out, x);
}

// Round 3
// 461.465 us; speedup vs baseline: 1.1861x; 1.1419x over previous
//
#include <hip/hip_runtime.h>

// ---------------------------------------------------------------------------
// AttnBlock: GroupNorm -> q,k,v 1x1 conv -> softmax(QK^T/sqrt(c)) V -> out
// conv -> residual.  b=4, c=512, h=w=64 (n=4096), 32 groups.
// R2: (1) XCD-affinity swizzle in flash (all q-blocks of one (b,s) K/V
//     working set on one XCD -> L2-resident), (2) fixed-shift softmax
//     (no online max / no per-iter cross-lane chains; safe: |sim|<<76),
//     (3) gemm128 staging via global_load_lds width=16 (m97 pattern).
// ---------------------------------------------------------------------------

typedef __attribute__((ext_vector_type(8))) short bf16x8;   // 8 bf16 (4 VGPR)
typedef __attribute__((ext_vector_type(4))) float f32x4;    // MFMA acc frag

#define MFMA16(a, b, c) __builtin_amdgcn_mfma_f32_16x16x32_bf16((a), (b), (c), 0, 0, 0)

#define B_   4
#define C_   512
#define N_   4096
#define G_   32
#define SCALE 0.044194173824159216f  // 1/sqrt(512)
#define ESHIFT 12.0f                 // uniform exp shift (overflow insurance)

__device__ __forceinline__ unsigned short f2bf(float f) {
    union { float f; unsigned int u; } v; v.f = f;
    unsigned int r = (v.u + 0x7fffu + ((v.u >> 16) & 1u)) >> 16;  // RNE
    return (unsigned short)r;
}
__device__ __forceinline__ float bf2f(unsigned short s) {
    union { unsigned int u; float f; } v; v.u = ((unsigned int)s) << 16;
    return v.f;
}

// async 16B global -> LDS (lane i lands at lds + i*16)
__device__ __forceinline__ void async16(const unsigned short* g, unsigned short* l) {
    __builtin_amdgcn_global_load_lds((const __attribute__((address_space(1))) unsigned int*)g,
                                     (__attribute__((address_space(3))) unsigned int*)l,
                                     16, 0, 0);
}

// ---------------- GroupNorm stats: one block per (b,g) ----------------------
__global__ __launch_bounds__(256) void gn_stats(const float* __restrict__ x,
                                                float* __restrict__ stats) {
    int blk = blockIdx.x;  // b*32 + g ; group = 16 channels * 4096 contiguous
    const float4* base = (const float4*)(x + (size_t)blk * 65536);
    float s = 0.f, ss = 0.f;
    for (int i = threadIdx.x; i < 16384; i += 256) {
        float4 v = base[i];
        s  += v.x + v.y + v.z + v.w;
        ss += v.x * v.x + v.y * v.y + v.z * v.z + v.w * v.w;
    }
    __shared__ float red[512];
    int t = threadIdx.x;
    red[t] = s; red[256 + t] = ss;
    __syncthreads();
    for (int st = 128; st > 0; st >>= 1) {
        if (t < st) { red[t] += red[t + st]; red[256 + t] += red[256 + t + st]; }
        __syncthreads();
    }
    if (t == 0) {
        float mean = red[0] * (1.f / 65536.f);
        float var  = red[256] * (1.f / 65536.f) - mean * mean;
        stats[blk] = mean;
        stats[128 + blk] = rsqrtf(var + 1e-6f);
    }
}

// ------------- GroupNorm apply + transpose -> Ht[b][n][c] bf16 --------------
__global__ __launch_bounds__(256) void gn_apply(const float* __restrict__ x,
                                                const float* __restrict__ gamma,
                                                const float* __restrict__ beta,
                                                const float* __restrict__ stats,
                                                unsigned short* __restrict__ ht) {
    __shared__ float tile[64][65];
    int j0 = blockIdx.x * 64, c0 = blockIdx.y * 64, b = blockIdx.z;
    int t = threadIdx.x;
#pragma unroll
    for (int i = 0; i < 16; ++i) {
        int lid = i * 256 + t;
        int cl = lid >> 6, jl = lid & 63;
        int c = c0 + cl, g = c >> 4;
        float mean = stats[b * 32 + g], rstd = stats[128 + b * 32 + g];
        float v = x[((size_t)b * C_ + c) * N_ + j0 + jl];
        tile[cl][jl] = (v - mean) * rstd * gamma[c] + beta[c];
    }
    __syncthreads();
#pragma unroll
    for (int i = 0; i < 16; ++i) {
        int lid = i * 256 + t;
        int jl = lid >> 6, cl = lid & 63;
        ht[((size_t)b * N_ + j0 + jl) * C_ + c0 + cl] = f2bf(tile[cl][jl]);
    }
}

// ------------- convert the 4 weight matrices to bf16 ------------------------
__global__ __launch_bounds__(256) void wconv(const float* __restrict__ wq,
                                             const float* __restrict__ wk,
                                             const float* __restrict__ wv,
                                             const float* __restrict__ wo,
                                             unsigned short* __restrict__ dst) {
    size_t i = (size_t)blockIdx.x * 256 + threadIdx.x;  // 4*512*512 total
    int m = (int)(i >> 18);
    size_t off = i & 262143;
    const float* src = (m == 0) ? wq : (m == 1) ? wk : (m == 2) ? wv : wo;
    dst[i] = f2bf(src[off]);
}

// ------------- 128x128x(K=512) bf16 GEMM, async staging (m97) ---------------
// MODE 0: out[b][j][co]; MODE 1: out[b][co][j] bf16; MODE 2: f32 + residual.
template <int MODE>
__global__ __launch_bounds__(256) void gemm128(const unsigned short* __restrict__ hsrc,
                                               const unsigned short* __restrict__ wsrc,
                                               const float* __restrict__ bias,
                                               unsigned short* __restrict__ outb,
                                               float* __restrict__ outf,
                                               const float* __restrict__ xres) {
    __shared__ unsigned short hl[128 * 64];  // unpadded: global_load_lds layout
    __shared__ unsigned short wl[128 * 64];
    int b = blockIdx.z;
    int j0 = blockIdx.x * 128, co0 = blockIdx.y * 128;
    int t = threadIdx.x;
    int wv = t >> 6, lane = t & 63, l15 = lane & 15, quad = lane >> 4;
    int wm = wv & 1, wn = wv >> 1;
    f32x4 acc[4][4] = {};
    for (int k0 = 0; k0 < 512; k0 += 64) {
        __syncthreads();  // prior compute done before overwrite
#pragma unroll
        for (int i = 0; i < 4; ++i) {
            int seg = wv * 4 + i;                 // 16 segs x 8 rows x 64 shorts
            int row = seg * 8 + (lane >> 3);
            int cc  = (lane & 7) * 8;
            async16(&hsrc[((size_t)b * N_ + j0 + row) * C_ + k0 + cc], &hl[seg * 512]);
            async16(&wsrc[(size_t)(co0 + row) * C_ + k0 + cc], &wl[seg * 512]);
        }
        __builtin_amdgcn_s_waitcnt(0x3F70);       // vmcnt(0)
        __syncthreads();
#pragma unroll
        for (int kk = 0; kk < 2; ++kk) {
            const unsigned short* ab = (MODE == 0) ? hl : wl;
            const unsigned short* bb = (MODE == 0) ? wl : hl;
            bf16x8 af[4], bfr[4];
#pragma unroll
            for (int mi = 0; mi < 4; ++mi)
                af[mi] = *(const bf16x8*)&ab[(wm * 64 + mi * 16 + l15) * 64 + kk * 32 + quad * 8];
#pragma unroll
            for (int ni = 0; ni < 4; ++ni)
                bfr[ni] = *(const bf16x8*)&bb[(wn * 64 + ni * 16 + l15) * 64 + kk * 32 + quad * 8];
#pragma unroll
            for (int mi = 0; mi < 4; ++mi)
#pragma unroll
                for (int ni = 0; ni < 4; ++ni)
                    acc[mi][ni] = MFMA16(af[mi], bfr[ni], acc[mi][ni]);
        }
    }
#pragma unroll
    for (int mi = 0; mi < 4; ++mi)
#pragma unroll
        for (int ni = 0; ni < 4; ++ni)
#pragma unroll
            for (int r = 0; r < 4; ++r) {
                int mrow = wm * 64 + mi * 16 + quad * 4 + r;
                int ncol = wn * 64 + ni * 16 + l15;
                float v = acc[mi][ni][r];
                if (MODE == 0) {
                    int j = j0 + mrow, co = co0 + ncol;
                    outb[((size_t)b * N_ + j) * C_ + co] = f2bf(v + bias[co]);
                } else {
                    int co = co0 + mrow, j = j0 + ncol;
                    size_t o = ((size_t)b * C_ + co) * N_ + j;
                    if (MODE == 1) outb[o] = f2bf(v + bias[co]);
                    else           outf[o] = v + bias[co] + xres[o];
                }
            }
}

// ------------- flash attention: async dbuf + XCD affinity + fixed-shift -----
// Qt,Kt: [b][n][c] bf16.  Vg: [b][c][n] bf16.
// Grid: 1-D, nsplit*B_*32 blocks. blockIdx%8 selects (b,s) so all 32
// q-blocks of one (b,s) land on one XCD (assuming blockIdx%8 -> XCD RR).
__global__ __launch_bounds__(512) void flash_attn(const unsigned short* __restrict__ Qt,
                                                  const unsigned short* __restrict__ Kt,
                                                  const unsigned short* __restrict__ Vg,
                                                  unsigned short* __restrict__ part,
                                                  float* __restrict__ lbuf,
                                                  int nsplit) {
    extern __shared__ unsigned short smem[];
    unsigned short* Kl = smem;            // 2 x 16384 shorts
    unsigned short* Vl = smem + 32768;    // 2 x 16384 shorts
    unsigned short* Pl = smem + 65536;    // 8 x 576 shorts

    int flat = blockIdx.x;
    int qblk, b, s;
    if (nsplit == 2) { s = flat & 1; b = (flat >> 1) & 3; qblk = flat >> 3; }
    else             { s = 0;        b = flat & 3;        qblk = flat >> 2; }
    int q0 = qblk * 128;
    int t = threadIdx.x, w = t >> 6, lane = t & 63, l15 = lane & 15, quad = lane >> 4;
    int klen = N_ / nsplit, kbeg = s * klen, nkt = klen / 32;
    int xr = l15 & 7;

    const unsigned short* Kbase = Kt + (size_t)b * N_ * C_;
    const unsigned short* Vbase = Vg + (size_t)b * C_ * N_;

    // Q fragments: 16 q rows per wave, A[m=l15][k=quad*8+j], 16 chunks of 32.
    bf16x8 qa[16];
    const unsigned short* qb = Qt + ((size_t)b * N_ + q0 + w * 16 + l15) * C_ + quad * 8;
#pragma unroll
    for (int ck = 0; ck < 16; ++ck) qa[ck] = *(const bf16x8*)(qb + ck * 32);

    f32x4 o[32] = {};
    float lrow[4] = {0.f, 0.f, 0.f, 0.f};

    // ---- stage tile 0 into buf 0 ----
    {
        int k0 = kbeg;
#pragma unroll
        for (int i = 0; i < 4; ++i) {
            int r = w * 4 + i;
            async16(Kbase + (size_t)(k0 + r) * C_ + ((lane ^ (r & 7)) * 8),
                    Kl + r * 512);
        }
#pragma unroll
        for (int i = 0; i < 4; ++i) {
            int idx = w * 4 + i, kc = idx >> 3, cb = idx & 7;
            async16(Vbase + (size_t)(cb * 64 + lane) * N_ + k0 + kc * 8,
                    Vl + (kc * 512 + cb * 64) * 8);
        }
    }

    for (int kt = 0; kt < nkt; ++kt) {
        int cur = kt & 1, nxt = cur ^ 1;
        __builtin_amdgcn_s_waitcnt(0x3F70);   // vmcnt(0): buf[cur] staged
        __syncthreads();
        if (kt + 1 < nkt) {                   // issue next tile, no wait
            int k0 = kbeg + (kt + 1) * 32;
#pragma unroll
            for (int i = 0; i < 4; ++i) {
                int r = w * 4 + i;
                async16(Kbase + (size_t)(k0 + r) * C_ + ((lane ^ (r & 7)) * 8),
                        Kl + nxt * 16384 + r * 512);
            }
#pragma unroll
            for (int i = 0; i < 4; ++i) {
                int idx = w * 4 + i, kc = idx >> 3, cb = idx & 7;
                async16(Vbase + (size_t)(cb * 64 + lane) * N_ + k0 + kc * 8,
                        Vl + nxt * 16384 + (kc * 512 + cb * 64) * 8);
            }
        }
        // ---- S = Q K^T over buf[cur] ----
        const unsigned short* Kc = Kl + cur * 16384;
        f32x4 s0 = {}, s1 = {};
#pragma unroll
        for (int ck = 0; ck < 16; ++ck) {
            int slot = (ck * 4 + quad) ^ xr;
            bf16x8 b0 = *(const bf16x8*)&Kc[l15 * 512 + slot * 8];
            bf16x8 b1 = *(const bf16x8*)&Kc[(16 + l15) * 512 + slot * 8];
            s0 = MFMA16(qa[ck], b0, s0);
            s1 = MFMA16(qa[ck], b1, s1);
        }
        // ---- fixed-shift softmax numerator: p = exp(v*scale - 12) ----
        unsigned short* pb = &Pl[w * 576];
#pragma unroll
        for (int r = 0; r < 4; ++r) {
            float p0 = __expf(s0[r] * SCALE - ESHIFT);
            float p1 = __expf(s1[r] * SCALE - ESHIFT);
            lrow[r] += p0 + p1;
            pb[(quad * 4 + r) * 36 + l15]      = f2bf(p0);
            pb[(quad * 4 + r) * 36 + 16 + l15] = f2bf(p1);
        }
        __builtin_amdgcn_s_waitcnt(0xC07F);  // lgkmcnt(0): P visible to own wave
        // ---- P V over buf[cur] ----
        bf16x8 pa = *(const bf16x8*)&Pl[w * 576 + l15 * 36 + quad * 8];
        const unsigned short* Vc = Vl + cur * 16384;
#pragma unroll
        for (int cf = 0; cf < 32; ++cf) {
            bf16x8 vb = *(const bf16x8*)&Vc[(quad * 512 + cf * 16 + l15) * 8];
            o[cf] = MFMA16(pa, vb, o[cf]);
        }
    }
    // ---- one-time l reduction across l15 lanes ----
#pragma unroll
    for (int r = 0; r < 4; ++r) {
        float l = lrow[r];
        l += __shfl_xor(l, 1);
        l += __shfl_xor(l, 2);
        l += __shfl_xor(l, 4);
        l += __shfl_xor(l, 8);
        lrow[r] = l;
    }
    // ---- write unnormalized partial + l ----
    size_t pbase = (size_t)(s * B_ + b) * N_;
#pragma unroll
    for (int cf = 0; cf < 32; ++cf)
#pragma unroll
        for (int r = 0; r < 4; ++r) {
            int q = q0 + w * 16 + quad * 4 + r;
            part[(pbase + q) * C_ + cf * 16 + l15] = f2bf(o[cf][r]);
        }
    if (l15 == 0) {
#pragma unroll
        for (int r = 0; r < 4; ++r) {
            int q = q0 + w * 16 + quad * 4 + r;
            lbuf[pbase + q] = lrow[r];
        }
    }
}

// ------------- combine split-K partials -> AObf[b][n][c] bf16 ---------------
__global__ __launch_bounds__(256) void attn_combine(const unsigned short* __restrict__ part,
                                                    const float* __restrict__ lbuf,
                                                    unsigned short* __restrict__ ao,
                                                    int nsplit) {
    size_t idx = (size_t)blockIdx.x * 256 + threadIdx.x;
    int cu = (int)(idx & 63);
    size_t row = idx >> 6;  // b*4096 + q
    float l = lbuf[row];
    union { uint4 v; unsigned short u[8]; } p1, p2, outv;
    p1.v = *(const uint4*)&part[row * C_ + cu * 8];
    if (nsplit == 2) {
        l += lbuf[(size_t)B_ * N_ + row];
        p2.v = *(const uint4*)&part[((size_t)B_ * N_ + row) * C_ + cu * 8];
    } else {
        p2.v = make_uint4(0, 0, 0, 0);
    }
    float inv = 1.f / l;
#pragma unroll
    for (int j = 0; j < 8; ++j)
        outv.u[j] = f2bf((bf2f(p1.u[j]) + bf2f(p2.u[j])) * inv);
    *(uint4*)&ao[row * C_ + cu * 8] = outv.v;
}

// ---------------------------------------------------------------------------
extern "C" void kernel_launch(void* const* d_in, const int* in_sizes, int n_in,
                              void* d_out, int out_size, void* d_ws, size_t ws_size,
                              hipStream_t stream) {
    const float* x   = (const float*)d_in[0];
    const float* gam = (const float*)d_in[1];
    const float* bet = (const float*)d_in[2];
    const float* wq  = (const float*)d_in[3];
    const float* bq  = (const float*)d_in[4];
    const float* wk  = (const float*)d_in[5];
    const float* bk  = (const float*)d_in[6];
    const float* wv  = (const float*)d_in[7];
    const float* bv  = (const float*)d_in[8];
    const float* wo  = (const float*)d_in[9];
    const float* bo  = (const float*)d_in[10];
    float* out = (float*)d_out;

    char* ws = (char*)d_ws;
    const size_t SZH = (size_t)B_ * N_ * C_ * 2;  // 16 MiB bf16 tensor
    float*          stats = (float*)ws;
    unsigned short* Ht    = (unsigned short*)(ws + 4096);
    unsigned short* Qt    = (unsigned short*)(ws + 4096 + SZH);
    unsigned short* Kt    = (unsigned short*)(ws + 4096 + 2 * SZH);
    unsigned short* Vg    = (unsigned short*)(ws + 4096 + 3 * SZH);
    unsigned short* Wb    = (unsigned short*)(ws + 4096 + 4 * SZH);
    float*          lbuf  = (float*)(ws + 4096 + 4 * SZH + 2097152 + 131072);
    unsigned short* part  = (unsigned short*)(ws + 4096 + 4 * SZH + 2097152 + 262144);
    size_t need2 = 4096 + 4 * SZH + 2097152 + 262144 + 2 * SZH;
    int nsplit = (ws_size >= need2) ? 2 : 1;  // deterministic per run
    unsigned short* AObf = Ht;

    const int FLASH_LDS = 140288;  // 2x32KB K + 2x32KB V + 9KB P
    (void)hipFuncSetAttribute((const void*)flash_attn,
                              hipFuncAttributeMaxDynamicSharedMemorySize, FLASH_LDS);

    gn_stats<<<128, 256, 0, stream>>>(x, stats);
    gn_apply<<<dim3(64, 8, B_), 256, 0, stream>>>(x, gam, bet, stats, Ht);
    wconv<<<4096, 256, 0, stream>>>(wq, wk, wv, wo, Wb);
    gemm128<0><<<dim3(32, 4, B_), 256, 0, stream>>>(Ht, Wb,          bq, Qt, nullptr, nullptr);
    gemm128<0><<<dim3(32, 4, B_), 256, 0, stream>>>(Ht, Wb + 262144, bk, Kt, nullptr, nullptr);
    gemm128<1><<<dim3(32, 4, B_), 256, 0, stream>>>(Ht, Wb + 524288, bv, Vg, nullptr, nullptr);
    flash_attn<<<dim3(32 * B_ * nsplit), 512, FLASH_LDS, stream>>>(Qt, Kt, Vg, part, lbuf, nsplit);
    attn_combine<<<4096, 256, 0, stream>>>(part, lbuf, AObf, nsplit);
    gemm128<2><<<dim3(32, 4, B_), 256, 0, stream>>>(AObf, Wb + 786432, bo, nullptr, out, x);
}

// Round 4
// 440.221 us; speedup vs baseline: 1.2434x; 1.0483x over previous
//
#include <hip/hip_runtime.h>

// ---------------------------------------------------------------------------
// AttnBlock: GroupNorm -> q,k,v 1x1 conv -> softmax(QK^T/sqrt(c)) V -> out
// conv -> residual.  b=4, c=512, h=w=64 (n=4096), 32 groups.
// R3: flash reorganized 8x16 -> 4x32 q-rows/wave (2 A-frags): every LDS
//     B-fragment read feeds 2 MFMAs, halving the LDS-read traffic that
//     R2 profiling showed to be ~75% of the iteration budget.
//     256-thread blocks, __launch_bounds__(256,1) for the 512-VGPR budget.
// ---------------------------------------------------------------------------

typedef __attribute__((ext_vector_type(8))) short bf16x8;   // 8 bf16 (4 VGPR)
typedef __attribute__((ext_vector_type(4))) float f32x4;    // MFMA acc frag

#define MFMA16(a, b, c) __builtin_amdgcn_mfma_f32_16x16x32_bf16((a), (b), (c), 0, 0, 0)

#define B_   4
#define C_   512
#define N_   4096
#define G_   32
#define SCALE 0.044194173824159216f  // 1/sqrt(512)
#define ESHIFT 12.0f                 // uniform exp shift (overflow insurance)

__device__ __forceinline__ unsigned short f2bf(float f) {
    union { float f; unsigned int u; } v; v.f = f;
    unsigned int r = (v.u + 0x7fffu + ((v.u >> 16) & 1u)) >> 16;  // RNE
    return (unsigned short)r;
}
__device__ __forceinline__ float bf2f(unsigned short s) {
    union { unsigned int u; float f; } v; v.u = ((unsigned int)s) << 16;
    return v.f;
}

// async 16B global -> LDS (lane i lands at lds + i*16)
__device__ __forceinline__ void async16(const unsigned short* g, unsigned short* l) {
    __builtin_amdgcn_global_load_lds((const __attribute__((address_space(1))) unsigned int*)g,
                                     (__attribute__((address_space(3))) unsigned int*)l,
                                     16, 0, 0);
}

// ---------------- GroupNorm stats: one block per (b,g) ----------------------
__global__ __launch_bounds__(256) void gn_stats(const float* __restrict__ x,
                                                float* __restrict__ stats) {
    int blk = blockIdx.x;  // b*32 + g ; group = 16 channels * 4096 contiguous
    const float4* base = (const float4*)(x + (size_t)blk * 65536);
    float s = 0.f, ss = 0.f;
    for (int i = threadIdx.x; i < 16384; i += 256) {
        float4 v = base[i];
        s  += v.x + v.y + v.z + v.w;
        ss += v.x * v.x + v.y * v.y + v.z * v.z + v.w * v.w;
    }
    __shared__ float red[512];
    int t = threadIdx.x;
    red[t] = s; red[256 + t] = ss;
    __syncthreads();
    for (int st = 128; st > 0; st >>= 1) {
        if (t < st) { red[t] += red[t + st]; red[256 + t] += red[256 + t + st]; }
        __syncthreads();
    }
    if (t == 0) {
        float mean = red[0] * (1.f / 65536.f);
        float var  = red[256] * (1.f / 65536.f) - mean * mean;
        stats[blk] = mean;
        stats[128 + blk] = rsqrtf(var + 1e-6f);
    }
}

// ------------- GroupNorm apply + transpose -> Ht[b][n][c] bf16 --------------
__global__ __launch_bounds__(256) void gn_apply(const float* __restrict__ x,
                                                const float* __restrict__ gamma,
                                                const float* __restrict__ beta,
                                                const float* __restrict__ stats,
                                                unsigned short* __restrict__ ht) {
    __shared__ float tile[64][65];
    int j0 = blockIdx.x * 64, c0 = blockIdx.y * 64, b = blockIdx.z;
    int t = threadIdx.x;
#pragma unroll
    for (int i = 0; i < 16; ++i) {
        int lid = i * 256 + t;
        int cl = lid >> 6, jl = lid & 63;
        int c = c0 + cl, g = c >> 4;
        float mean = stats[b * 32 + g], rstd = stats[128 + b * 32 + g];
        float v = x[((size_t)b * C_ + c) * N_ + j0 + jl];
        tile[cl][jl] = (v - mean) * rstd * gamma[c] + beta[c];
    }
    __syncthreads();
#pragma unroll
    for (int i = 0; i < 16; ++i) {
        int lid = i * 256 + t;
        int jl = lid >> 6, cl = lid & 63;
        ht[((size_t)b * N_ + j0 + jl) * C_ + c0 + cl] = f2bf(tile[cl][jl]);
    }
}

// ------------- convert the 4 weight matrices to bf16 ------------------------
__global__ __launch_bounds__(256) void wconv(const float* __restrict__ wq,
                                             const float* __restrict__ wk,
                                             const float* __restrict__ wv,
                                             const float* __restrict__ wo,
                                             unsigned short* __restrict__ dst) {
    size_t i = (size_t)blockIdx.x * 256 + threadIdx.x;  // 4*512*512 total
    int m = (int)(i >> 18);
    size_t off = i & 262143;
    const float* src = (m == 0) ? wq : (m == 1) ? wk : (m == 2) ? wv : wo;
    dst[i] = f2bf(src[off]);
}

// ------------- 128x128x(K=512) bf16 GEMM, async staging (m97) ---------------
// MODE 0: out[b][j][co]; MODE 1: out[b][co][j] bf16; MODE 2: f32 + residual.
template <int MODE>
__global__ __launch_bounds__(256) void gemm128(const unsigned short* __restrict__ hsrc,
                                               const unsigned short* __restrict__ wsrc,
                                               const float* __restrict__ bias,
                                               unsigned short* __restrict__ outb,
                                               float* __restrict__ outf,
                                               const float* __restrict__ xres) {
    __shared__ unsigned short hl[128 * 64];  // unpadded: global_load_lds layout
    __shared__ unsigned short wl[128 * 64];
    int b = blockIdx.z;
    int j0 = blockIdx.x * 128, co0 = blockIdx.y * 128;
    int t = threadIdx.x;
    int wv = t >> 6, lane = t & 63, l15 = lane & 15, quad = lane >> 4;
    int wm = wv & 1, wn = wv >> 1;
    f32x4 acc[4][4] = {};
    for (int k0 = 0; k0 < 512; k0 += 64) {
        __syncthreads();  // prior compute done before overwrite
#pragma unroll
        for (int i = 0; i < 4; ++i) {
            int seg = wv * 4 + i;                 // 16 segs x 8 rows x 64 shorts
            int row = seg * 8 + (lane >> 3);
            int cc  = (lane & 7) * 8;
            async16(&hsrc[((size_t)b * N_ + j0 + row) * C_ + k0 + cc], &hl[seg * 512]);
            async16(&wsrc[(size_t)(co0 + row) * C_ + k0 + cc], &wl[seg * 512]);
        }
        __builtin_amdgcn_s_waitcnt(0x3F70);       // vmcnt(0)
        __syncthreads();
#pragma unroll
        for (int kk = 0; kk < 2; ++kk) {
            const unsigned short* ab = (MODE == 0) ? hl : wl;
            const unsigned short* bb = (MODE == 0) ? wl : hl;
            bf16x8 af[4], bfr[4];
#pragma unroll
            for (int mi = 0; mi < 4; ++mi)
                af[mi] = *(const bf16x8*)&ab[(wm * 64 + mi * 16 + l15) * 64 + kk * 32 + quad * 8];
#pragma unroll
            for (int ni = 0; ni < 4; ++ni)
                bfr[ni] = *(const bf16x8*)&bb[(wn * 64 + ni * 16 + l15) * 64 + kk * 32 + quad * 8];
#pragma unroll
            for (int mi = 0; mi < 4; ++mi)
#pragma unroll
                for (int ni = 0; ni < 4; ++ni)
                    acc[mi][ni] = MFMA16(af[mi], bfr[ni], acc[mi][ni]);
        }
    }
#pragma unroll
    for (int mi = 0; mi < 4; ++mi)
#pragma unroll
        for (int ni = 0; ni < 4; ++ni)
#pragma unroll
            for (int r = 0; r < 4; ++r) {
                int mrow = wm * 64 + mi * 16 + quad * 4 + r;
                int ncol = wn * 64 + ni * 16 + l15;
                float v = acc[mi][ni][r];
                if (MODE == 0) {
                    int j = j0 + mrow, co = co0 + ncol;
                    outb[((size_t)b * N_ + j) * C_ + co] = f2bf(v + bias[co]);
                } else {
                    int co = co0 + mrow, j = j0 + ncol;
                    size_t o = ((size_t)b * C_ + co) * N_ + j;
                    if (MODE == 1) outb[o] = f2bf(v + bias[co]);
                    else           outf[o] = v + bias[co] + xres[o];
                }
            }
}

// ------------- flash attention: 4 waves x 32 q-rows, B-frag reuse x2 --------
// Qt,Kt: [b][n][c] bf16.  Vg: [b][c][n] bf16.
// Grid 1-D: blockIdx%8 -> (b,s) for XCD L2 affinity; 256 threads.
// Dynamic LDS 140,288 B: K dbuf 64K, V dbuf 64K, P 4x32x36 shorts.
__global__ __launch_bounds__(256, 1) void flash_attn(const unsigned short* __restrict__ Qt,
                                                     const unsigned short* __restrict__ Kt,
                                                     const unsigned short* __restrict__ Vg,
                                                     unsigned short* __restrict__ part,
                                                     float* __restrict__ lbuf,
                                                     int nsplit) {
    extern __shared__ unsigned short smem[];
    unsigned short* Kl = smem;            // 2 x 16384 shorts
    unsigned short* Vl = smem + 32768;    // 2 x 16384 shorts
    unsigned short* Pl = smem + 65536;    // 4 waves x 32 x 36 shorts

    int flat = blockIdx.x;
    int qblk, b, s;
    if (nsplit == 2) { s = flat & 1; b = (flat >> 1) & 3; qblk = flat >> 3; }
    else             { s = 0;        b = flat & 3;        qblk = flat >> 2; }
    int q0 = qblk * 128;
    int t = threadIdx.x, w = t >> 6, lane = t & 63, l15 = lane & 15, quad = lane >> 4;
    int klen = N_ / nsplit, kbeg = s * klen, nkt = klen / 32;
    int xr = l15 & 7;

    const unsigned short* Kbase = Kt + (size_t)b * N_ * C_;
    const unsigned short* Vbase = Vg + (size_t)b * C_ * N_;

    // Q fragments: 32 q rows per wave (2 subgroups of 16), 16 k-chunks of 32.
    bf16x8 qa[2][16];
#pragma unroll
    for (int u = 0; u < 2; ++u) {
        const unsigned short* qb =
            Qt + ((size_t)b * N_ + q0 + w * 32 + u * 16 + l15) * C_ + quad * 8;
#pragma unroll
        for (int ck = 0; ck < 16; ++ck) qa[u][ck] = *(const bf16x8*)(qb + ck * 32);
    }

    f32x4 o[2][32] = {};
    float lrow[2][4] = {};

    // ---- stage tile 0 into buf 0 (8 K rows + 8 V segs per wave) ----
    {
        int k0 = kbeg;
#pragma unroll
        for (int i = 0; i < 8; ++i) {
            int r = w * 8 + i;
            async16(Kbase + (size_t)(k0 + r) * C_ + ((lane ^ (r & 7)) * 8),
                    Kl + r * 512);
        }
#pragma unroll
        for (int i = 0; i < 8; ++i) {
            int idx = w * 8 + i, kc = idx >> 3, cb = idx & 7;
            async16(Vbase + (size_t)(cb * 64 + lane) * N_ + k0 + kc * 8,
                    Vl + (kc * 512 + cb * 64) * 8);
        }
    }

    for (int kt = 0; kt < nkt; ++kt) {
        int cur = kt & 1, nxt = cur ^ 1;
        __builtin_amdgcn_s_waitcnt(0x3F70);   // vmcnt(0): buf[cur] staged
        __syncthreads();
        if (kt + 1 < nkt) {                   // issue next tile, no wait
            int k0 = kbeg + (kt + 1) * 32;
#pragma unroll
            for (int i = 0; i < 8; ++i) {
                int r = w * 8 + i;
                async16(Kbase + (size_t)(k0 + r) * C_ + ((lane ^ (r & 7)) * 8),
                        Kl + nxt * 16384 + r * 512);
            }
#pragma unroll
            for (int i = 0; i < 8; ++i) {
                int idx = w * 8 + i, kc = idx >> 3, cb = idx & 7;
                async16(Vbase + (size_t)(cb * 64 + lane) * N_ + k0 + kc * 8,
                        Vl + nxt * 16384 + (kc * 512 + cb * 64) * 8);
            }
        }
        // ---- S = Q K^T over buf[cur]: each B-frag feeds both q-subgroups ----
        const unsigned short* Kc = Kl + cur * 16384;
        f32x4 s00 = {}, s01 = {}, s10 = {}, s11 = {};
#pragma unroll
        for (int ck = 0; ck < 16; ++ck) {
            int slot = (ck * 4 + quad) ^ xr;
            bf16x8 b0 = *(const bf16x8*)&Kc[l15 * 512 + slot * 8];
            bf16x8 b1 = *(const bf16x8*)&Kc[(16 + l15) * 512 + slot * 8];
            s00 = MFMA16(qa[0][ck], b0, s00);
            s10 = MFMA16(qa[1][ck], b0, s10);
            s01 = MFMA16(qa[0][ck], b1, s01);
            s11 = MFMA16(qa[1][ck], b1, s11);
        }
        // ---- fixed-shift softmax numerator: p = exp(v*scale - 12) ----
        unsigned short* pb = &Pl[w * 1152];
#pragma unroll
        for (int r = 0; r < 4; ++r) {
            float p00 = __expf(s00[r] * SCALE - ESHIFT);
            float p01 = __expf(s01[r] * SCALE - ESHIFT);
            float p10 = __expf(s10[r] * SCALE - ESHIFT);
            float p11 = __expf(s11[r] * SCALE - ESHIFT);
            lrow[0][r] += p00 + p01;
            lrow[1][r] += p10 + p11;
            int row0 = (quad * 4 + r) * 36;
            int row1 = (16 + quad * 4 + r) * 36;
            pb[row0 + l15]      = f2bf(p00);
            pb[row0 + 16 + l15] = f2bf(p01);
            pb[row1 + l15]      = f2bf(p10);
            pb[row1 + 16 + l15] = f2bf(p11);
        }
        __builtin_amdgcn_s_waitcnt(0xC07F);  // lgkmcnt(0): P visible to own wave
        // ---- P V over buf[cur]: each V-frag feeds both q-subgroups ----
        bf16x8 pa0 = *(const bf16x8*)&Pl[w * 1152 + l15 * 36 + quad * 8];
        bf16x8 pa1 = *(const bf16x8*)&Pl[w * 1152 + (16 + l15) * 36 + quad * 8];
        const unsigned short* Vc = Vl + cur * 16384;
#pragma unroll
        for (int cf = 0; cf < 32; ++cf) {
            bf16x8 vb = *(const bf16x8*)&Vc[(quad * 512 + cf * 16 + l15) * 8];
            o[0][cf] = MFMA16(pa0, vb, o[0][cf]);
            o[1][cf] = MFMA16(pa1, vb, o[1][cf]);
        }
    }
    // ---- one-time l reduction across l15 lanes ----
#pragma unroll
    for (int u = 0; u < 2; ++u)
#pragma unroll
        for (int r = 0; r < 4; ++r) {
            float l = lrow[u][r];
            l += __shfl_xor(l, 1);
            l += __shfl_xor(l, 2);
            l += __shfl_xor(l, 4);
            l += __shfl_xor(l, 8);
            lrow[u][r] = l;
        }
    // ---- write unnormalized partial + l ----
    size_t pbase = (size_t)(s * B_ + b) * N_;
#pragma unroll
    for (int u = 0; u < 2; ++u)
#pragma unroll
        for (int cf = 0; cf < 32; ++cf)
#pragma unroll
            for (int r = 0; r < 4; ++r) {
                int q = q0 + w * 32 + u * 16 + quad * 4 + r;
                part[(pbase + q) * C_ + cf * 16 + l15] = f2bf(o[u][cf][r]);
            }
    if (l15 == 0) {
#pragma unroll
        for (int u = 0; u < 2; ++u)
#pragma unroll
            for (int r = 0; r < 4; ++r) {
                int q = q0 + w * 32 + u * 16 + quad * 4 + r;
                lbuf[pbase + q] = lrow[u][r];
            }
    }
}

// ------------- combine split-K partials -> AObf[b][n][c] bf16 ---------------
__global__ __launch_bounds__(256) void attn_combine(const unsigned short* __restrict__ part,
                                                    const float* __restrict__ lbuf,
                                                    unsigned short* __restrict__ ao,
                                                    int nsplit) {
    size_t idx = (size_t)blockIdx.x * 256 + threadIdx.x;
    int cu = (int)(idx & 63);
    size_t row = idx >> 6;  // b*4096 + q
    float l = lbuf[row];
    union { uint4 v; unsigned short u[8]; } p1, p2, outv;
    p1.v = *(const uint4*)&part[row * C_ + cu * 8];
    if (nsplit == 2) {
        l += lbuf[(size_t)B_ * N_ + row];
        p2.v = *(const uint4*)&part[((size_t)B_ * N_ + row) * C_ + cu * 8];
    } else {
        p2.v = make_uint4(0, 0, 0, 0);
    }
    float inv = 1.f / l;
#pragma unroll
    for (int j = 0; j < 8; ++j)
        outv.u[j] = f2bf((bf2f(p1.u[j]) + bf2f(p2.u[j])) * inv);
    *(uint4*)&ao[row * C_ + cu * 8] = outv.v;
}

// ---------------------------------------------------------------------------
extern "C" void kernel_launch(void* const* d_in, const int* in_sizes, int n_in,
                              void* d_out, int out_size, void* d_ws, size_t ws_size,
                              hipStream_t stream) {
    const float* x   = (const float*)d_in[0];
    const float* gam = (const float*)d_in[1];
    const float* bet = (const float*)d_in[2];
    const float* wq  = (const float*)d_in[3];
    const float* bq  = (const float*)d_in[4];
    const float* wk  = (const float*)d_in[5];
    const float* bk  = (const float*)d_in[6];
    const float* wv  = (const float*)d_in[7];
    const float* bv  = (const float*)d_in[8];
    const float* wo  = (const float*)d_in[9];
    const float* bo  = (const float*)d_in[10];
    float* out = (float*)d_out;

    char* ws = (char*)d_ws;
    const size_t SZH = (size_t)B_ * N_ * C_ * 2;  // 16 MiB bf16 tensor
    float*          stats = (float*)ws;
    unsigned short* Ht    = (unsigned short*)(ws + 4096);
    unsigned short* Qt    = (unsigned short*)(ws + 4096 + SZH);
    unsigned short* Kt    = (unsigned short*)(ws + 4096 + 2 * SZH);
    unsigned short* Vg    = (unsigned short*)(ws + 4096 + 3 * SZH);
    unsigned short* Wb    = (unsigned short*)(ws + 4096 + 4 * SZH);
    float*          lbuf  = (float*)(ws + 4096 + 4 * SZH + 2097152 + 131072);
    unsigned short* part  = (unsigned short*)(ws + 4096 + 4 * SZH + 2097152 + 262144);
    size_t need2 = 4096 + 4 * SZH + 2097152 + 262144 + 2 * SZH;
    int nsplit = (ws_size >= need2) ? 2 : 1;  // deterministic per run
    unsigned short* AObf = Ht;

    const int FLASH_LDS = 140288;  // 2x32KB K + 2x32KB V + 9KB P
    (void)hipFuncSetAttribute((const void*)flash_attn,
                              hipFuncAttributeMaxDynamicSharedMemorySize, FLASH_LDS);

    gn_stats<<<128, 256, 0, stream>>>(x, stats);
    gn_apply<<<dim3(64, 8, B_), 256, 0, stream>>>(x, gam, bet, stats, Ht);
    wconv<<<4096, 256, 0, stream>>>(wq, wk, wv, wo, Wb);
    gemm128<0><<<dim3(32, 4, B_), 256, 0, stream>>>(Ht, Wb,          bq, Qt, nullptr, nullptr);
    gemm128<0><<<dim3(32, 4, B_), 256, 0, stream>>>(Ht, Wb + 262144, bk, Kt, nullptr, nullptr);
    gemm128<1><<<dim3(32, 4, B_), 256, 0, stream>>>(Ht, Wb + 524288, bv, Vg, nullptr, nullptr);
    flash_attn<<<dim3(32 * B_ * nsplit), 256, FLASH_LDS, stream>>>(Qt, Kt, Vg, part, lbuf, nsplit);
    attn_combine<<<4096, 256, 0, stream>>>(part, lbuf, AObf, nsplit);
    gemm128<2><<<dim3(32, 4, B_), 256, 0, stream>>>(AObf, Wb + 786432, bo, nullptr, out, x);
}

// Round 5
// 423.396 us; speedup vs baseline: 1.2928x; 1.0397x over previous
//
#include <hip/hip_runtime.h>

// ---------------------------------------------------------------------------
// AttnBlock: GroupNorm -> q,k,v 1x1 conv -> softmax(QK^T/sqrt(c)) V -> out
// conv -> residual.  b=4, c=512, h=w=64 (n=4096), 32 groups.
// R5: attention as TWO m97-style GEMMs with materialized bf16 P
//     (fixed-shift exp, rowsum partials in GEMM1 epilogue, 1/l in GEMM2
//     epilogue). Flash path kept as fallback if ws_size < ~198 MB.
//     QKV projections fused into one launch via shared gemm_core.
// ---------------------------------------------------------------------------

typedef __attribute__((ext_vector_type(8))) short bf16x8;   // 8 bf16 (4 VGPR)
typedef __attribute__((ext_vector_type(4))) float f32x4;    // MFMA acc frag

#define MFMA16(a, b, c) __builtin_amdgcn_mfma_f32_16x16x32_bf16((a), (b), (c), 0, 0, 0)

#define B_   4
#define C_   512
#define N_   4096
#define SCALE 0.044194173824159216f  // 1/sqrt(512)
#define ESHIFT 12.0f                 // uniform exp shift (overflow insurance)

__device__ __forceinline__ unsigned short f2bf(float f) {
    union { float f; unsigned int u; } v; v.f = f;
    unsigned int r = (v.u + 0x7fffu + ((v.u >> 16) & 1u)) >> 16;  // RNE
    return (unsigned short)r;
}
__device__ __forceinline__ float bf2f(unsigned short s) {
    union { unsigned int u; float f; } v; v.u = ((unsigned int)s) << 16;
    return v.f;
}

// async 16B global -> LDS (lane i lands at lds + i*16)
__device__ __forceinline__ void async16(const unsigned short* g, unsigned short* l) {
    __builtin_amdgcn_global_load_lds((const __attribute__((address_space(1))) unsigned int*)g,
                                     (__attribute__((address_space(3))) unsigned int*)l,
                                     16, 0, 0);
}

// ---------------- GroupNorm stats: one block per (b,g) ----------------------
__global__ __launch_bounds__(256) void gn_stats(const float* __restrict__ x,
                                                float* __restrict__ stats) {
    int blk = blockIdx.x;  // b*32 + g
    const float4* base = (const float4*)(x + (size_t)blk * 65536);
    float s = 0.f, ss = 0.f;
    for (int i = threadIdx.x; i < 16384; i += 256) {
        float4 v = base[i];
        s  += v.x + v.y + v.z + v.w;
        ss += v.x * v.x + v.y * v.y + v.z * v.z + v.w * v.w;
    }
    __shared__ float red[512];
    int t = threadIdx.x;
    red[t] = s; red[256 + t] = ss;
    __syncthreads();
    for (int st = 128; st > 0; st >>= 1) {
        if (t < st) { red[t] += red[t + st]; red[256 + t] += red[256 + t + st]; }
        __syncthreads();
    }
    if (t == 0) {
        float mean = red[0] * (1.f / 65536.f);
        float var  = red[256] * (1.f / 65536.f) - mean * mean;
        stats[blk] = mean;
        stats[128 + blk] = rsqrtf(var + 1e-6f);
    }
}

// ------------- GroupNorm apply + transpose -> Ht[b][n][c] bf16 --------------
__global__ __launch_bounds__(256) void gn_apply(const float* __restrict__ x,
                                                const float* __restrict__ gamma,
                                                const float* __restrict__ beta,
                                                const float* __restrict__ stats,
                                                unsigned short* __restrict__ ht) {
    __shared__ float tile[64][65];
    int j0 = blockIdx.x * 64, c0 = blockIdx.y * 64, b = blockIdx.z;
    int t = threadIdx.x;
#pragma unroll
    for (int i = 0; i < 16; ++i) {
        int lid = i * 256 + t;
        int cl = lid >> 6, jl = lid & 63;
        int c = c0 + cl, g = c >> 4;
        float mean = stats[b * 32 + g], rstd = stats[128 + b * 32 + g];
        float v = x[((size_t)b * C_ + c) * N_ + j0 + jl];
        tile[cl][jl] = (v - mean) * rstd * gamma[c] + beta[c];
    }
    __syncthreads();
#pragma unroll
    for (int i = 0; i < 16; ++i) {
        int lid = i * 256 + t;
        int jl = lid >> 6, cl = lid & 63;
        ht[((size_t)b * N_ + j0 + jl) * C_ + c0 + cl] = f2bf(tile[cl][jl]);
    }
}

// ------------- convert the 4 weight matrices to bf16 ------------------------
__global__ __launch_bounds__(256) void wconv(const float* __restrict__ wq,
                                             const float* __restrict__ wk,
                                             const float* __restrict__ wv,
                                             const float* __restrict__ wo,
                                             unsigned short* __restrict__ dst) {
    size_t i = (size_t)blockIdx.x * 256 + threadIdx.x;  // 4*512*512 total
    int m = (int)(i >> 18);
    size_t off = i & 262143;
    const float* src = (m == 0) ? wq : (m == 1) ? wk : (m == 2) ? wv : wo;
    dst[i] = f2bf(src[off]);
}

// ------------- shared 128x128xK MFMA GEMM core (m97 staging) ----------------
// A: [128 rows][K] row-major (lda), B: [128 rows][K] row-major (ldb).
// acc[m=A-row][n=B-row]; epilogue epi(acc, wm, wn, l15, quad).
template <typename EPI>
__device__ __forceinline__ void gemm_core(const unsigned short* __restrict__ Abase,
                                          const unsigned short* __restrict__ Bbase,
                                          size_t lda, size_t ldb, int K, EPI epi) {
    __shared__ unsigned short hl[128 * 64];
    __shared__ unsigned short wl[128 * 64];
    int t = threadIdx.x;
    int wv = t >> 6, lane = t & 63, l15 = lane & 15, quad = lane >> 4;
    int wm = wv & 1, wn = wv >> 1;
    int rowoff = lane >> 3, coloff = (lane & 7) * 8;
    f32x4 acc[4][4] = {};
    for (int k0 = 0; k0 < K; k0 += 64) {
        __syncthreads();  // prior compute done before overwrite
#pragma unroll
        for (int i = 0; i < 4; ++i) {
            int seg = wv * 4 + i;                 // 16 segs x 8 rows x 64 shorts
            int row = seg * 8 + rowoff;
            async16(&Abase[(size_t)row * lda + k0 + coloff], &hl[seg * 512]);
            async16(&Bbase[(size_t)row * ldb + k0 + coloff], &wl[seg * 512]);
        }
        __builtin_amdgcn_s_waitcnt(0x3F70);       // vmcnt(0)
        __syncthreads();
#pragma unroll
        for (int kk = 0; kk < 2; ++kk) {
            bf16x8 af[4], bfr[4];
#pragma unroll
            for (int mi = 0; mi < 4; ++mi)
                af[mi] = *(const bf16x8*)&hl[(wm * 64 + mi * 16 + l15) * 64 + kk * 32 + quad * 8];
#pragma unroll
            for (int ni = 0; ni < 4; ++ni)
                bfr[ni] = *(const bf16x8*)&wl[(wn * 64 + ni * 16 + l15) * 64 + kk * 32 + quad * 8];
#pragma unroll
            for (int mi = 0; mi < 4; ++mi)
#pragma unroll
                for (int ni = 0; ni < 4; ++ni)
                    acc[mi][ni] = MFMA16(af[mi], bfr[ni], acc[mi][ni]);
        }
    }
    epi(acc, wm, wn, l15, quad);
}

// ------------- fused QKV projection: grid (32, 12, 4) -----------------------
__global__ __launch_bounds__(256) void gemm_qkv(const unsigned short* __restrict__ Ht,
                                                const unsigned short* __restrict__ Wb,
                                                const float* __restrict__ bq,
                                                const float* __restrict__ bk,
                                                const float* __restrict__ bv,
                                                unsigned short* __restrict__ Qt,
                                                unsigned short* __restrict__ Kt,
                                                unsigned short* __restrict__ Vg) {
    int b = blockIdx.z, j0 = blockIdx.x * 128;
    int ct = blockIdx.y;                 // 0..11
    int slab = ct >> 2, co0 = (ct & 3) * 128;
    const unsigned short* A = Ht + ((size_t)b * N_ + j0) * C_;
    const unsigned short* B = Wb + (size_t)slab * C_ * C_ + (size_t)co0 * C_;
    const float* bias = (slab == 0) ? bq : (slab == 1) ? bk : bv;
    unsigned short* outqk = (slab == 0) ? Qt : Kt;
    gemm_core(A, B, C_, C_, C_,
        [&](f32x4 (&acc)[4][4], int wm, int wn, int l15, int quad) {
        if (slab < 2) {
#pragma unroll
            for (int mi = 0; mi < 4; ++mi)
#pragma unroll
                for (int ni = 0; ni < 4; ++ni)
#pragma unroll
                    for (int r = 0; r < 4; ++r) {
                        int mrow = wm * 64 + mi * 16 + quad * 4 + r;
                        int ncol = wn * 64 + ni * 16 + l15;
                        outqk[((size_t)b * N_ + j0 + mrow) * C_ + co0 + ncol] =
                            f2bf(acc[mi][ni][r] + bias[co0 + ncol]);
                    }
        } else {
#pragma unroll
            for (int mi = 0; mi < 4; ++mi)
#pragma unroll
                for (int ni = 0; ni < 4; ++ni) {
                    int ncol = wn * 64 + ni * 16 + l15;
                    float bb = bias[co0 + ncol];
                    ushort4 pk;
                    pk.x = f2bf(acc[mi][ni][0] + bb);
                    pk.y = f2bf(acc[mi][ni][1] + bb);
                    pk.z = f2bf(acc[mi][ni][2] + bb);
                    pk.w = f2bf(acc[mi][ni][3] + bb);
                    int jb = j0 + wm * 64 + mi * 16 + quad * 4;
                    *(ushort4*)&Vg[((size_t)b * C_ + co0 + ncol) * N_ + jb] = pk;
                }
        }
    });
}

// ------------- GEMM1: P = exp(Q K^T * scale - 12), rowsum partials ----------
// grid (32, 32, 4).  psum layout: [wn*32+ktile][b*4096+q] f32 (64 x 16384).
__global__ __launch_bounds__(256) void gemm_qk_exp(const unsigned short* __restrict__ Qt,
                                                   const unsigned short* __restrict__ Kt,
                                                   unsigned short* __restrict__ P,
                                                   float* __restrict__ psum) {
    int b = blockIdx.z, j0 = blockIdx.x * 128, ktile = blockIdx.y;
    int kc0 = ktile * 128;
    const unsigned short* A = Qt + ((size_t)b * N_ + j0) * C_;
    const unsigned short* B = Kt + ((size_t)b * N_ + kc0) * C_;
    gemm_core(A, B, C_, C_, C_,
        [&](f32x4 (&acc)[4][4], int wm, int wn, int l15, int quad) {
        float rs[4][4];
#pragma unroll
        for (int mi = 0; mi < 4; ++mi)
#pragma unroll
            for (int r = 0; r < 4; ++r) rs[mi][r] = 0.f;
#pragma unroll
        for (int mi = 0; mi < 4; ++mi)
#pragma unroll
            for (int ni = 0; ni < 4; ++ni)
#pragma unroll
                for (int r = 0; r < 4; ++r) {
                    int mrow = wm * 64 + mi * 16 + quad * 4 + r;
                    int ncol = wn * 64 + ni * 16 + l15;
                    float p = __expf(acc[mi][ni][r] * SCALE - ESHIFT);
                    rs[mi][r] += p;
                    P[((size_t)b * N_ + j0 + mrow) * N_ + kc0 + ncol] = f2bf(p);
                }
#pragma unroll
        for (int mi = 0; mi < 4; ++mi)
#pragma unroll
            for (int r = 0; r < 4; ++r) {
                float v = rs[mi][r];
                v += __shfl_xor(v, 1);
                v += __shfl_xor(v, 2);
                v += __shfl_xor(v, 4);
                v += __shfl_xor(v, 8);
                if (l15 == 0)
                    psum[(size_t)(wn * 32 + ktile) * 16384 +
                         (size_t)b * N_ + j0 + wm * 64 + mi * 16 + quad * 4 + r] = v;
            }
    });
}

// ------------- GEMM2: O = (P V) / l -> AObf[b][n][c] bf16 -------------------
// flat grid 512, XCD-grouped: the 4 c-tiles sharing a P row-tile colocate.
__global__ __launch_bounds__(256) void gemm_pv(const unsigned short* __restrict__ P,
                                               const unsigned short* __restrict__ Vg,
                                               const float* __restrict__ psum,
                                               unsigned short* __restrict__ ao) {
    __shared__ float linv[128];
    int flat = blockIdx.x;
    int xcd = flat & 7, rr = flat >> 3;
    int ct = rr & 3, g = (rr >> 2) * 8 + xcd;   // g in [0,128)
    int b = g & 3, qtile = g >> 2;
    int j0 = qtile * 128, co0 = ct * 128;
    int t = threadIdx.x;
    if (t < 128) {
        size_t q = (size_t)b * N_ + j0 + t;
        float s = 0.f;
#pragma unroll
        for (int i = 0; i < 64; ++i) s += psum[(size_t)i * 16384 + q];
        linv[t] = 1.f / s;
    }
    const unsigned short* A = P + ((size_t)b * N_ + j0) * N_;
    const unsigned short* B = Vg + ((size_t)b * C_ + co0) * N_;
    gemm_core(A, B, N_, N_, N_,
        [&](f32x4 (&acc)[4][4], int wm, int wn, int l15, int quad) {
#pragma unroll
        for (int mi = 0; mi < 4; ++mi)
#pragma unroll
            for (int ni = 0; ni < 4; ++ni)
#pragma unroll
                for (int r = 0; r < 4; ++r) {
                    int mrow = wm * 64 + mi * 16 + quad * 4 + r;
                    int ncol = wn * 64 + ni * 16 + l15;
                    ao[((size_t)b * N_ + j0 + mrow) * C_ + co0 + ncol] =
                        f2bf(acc[mi][ni][r] * linv[mrow]);
                }
    });
}

// ------------- final projection + residual: grid (32, 4, 4) -----------------
__global__ __launch_bounds__(256) void gemm_resid(const unsigned short* __restrict__ AObf,
                                                  const unsigned short* __restrict__ Wo,
                                                  const float* __restrict__ bo,
                                                  const float* __restrict__ xres,
                                                  float* __restrict__ out) {
    int b = blockIdx.z, j0 = blockIdx.x * 128, co0 = blockIdx.y * 128;
    const unsigned short* A = AObf + ((size_t)b * N_ + j0) * C_;
    const unsigned short* B = Wo + (size_t)co0 * C_;
    gemm_core(A, B, C_, C_, C_,
        [&](f32x4 (&acc)[4][4], int wm, int wn, int l15, int quad) {
#pragma unroll
        for (int mi = 0; mi < 4; ++mi)
#pragma unroll
            for (int ni = 0; ni < 4; ++ni) {
                int ncol = wn * 64 + ni * 16 + l15;
                int jb = j0 + wm * 64 + mi * 16 + quad * 4;
                size_t o = ((size_t)b * C_ + co0 + ncol) * N_ + jb;
                float bb = bo[co0 + ncol];
                float4 xr = *(const float4*)&xres[o];
                float4 ov;
                ov.x = acc[mi][ni][0] + bb + xr.x;
                ov.y = acc[mi][ni][1] + bb + xr.y;
                ov.z = acc[mi][ni][2] + bb + xr.z;
                ov.w = acc[mi][ni][3] + bb + xr.w;
                *(float4*)&out[o] = ov;
            }
    });
}

// ------------- FALLBACK: R4 flash attention (if ws too small) ---------------
__global__ __launch_bounds__(256, 1) void flash_attn(const unsigned short* __restrict__ Qt,
                                                     const unsigned short* __restrict__ Kt,
                                                     const unsigned short* __restrict__ Vg,
                                                     unsigned short* __restrict__ part,
                                                     float* __restrict__ lbuf,
                                                     int nsplit) {
    extern __shared__ unsigned short smem[];
    unsigned short* Kl = smem;
    unsigned short* Vl = smem + 32768;
    unsigned short* Pl = smem + 65536;

    int flat = blockIdx.x;
    int qblk, b, s;
    if (nsplit == 2) { s = flat & 1; b = (flat >> 1) & 3; qblk = flat >> 3; }
    else             { s = 0;        b = flat & 3;        qblk = flat >> 2; }
    int q0 = qblk * 128;
    int t = threadIdx.x, w = t >> 6, lane = t & 63, l15 = lane & 15, quad = lane >> 4;
    int klen = N_ / nsplit, kbeg = s * klen, nkt = klen / 32;
    int xr = l15 & 7;

    const unsigned short* Kbase = Kt + (size_t)b * N_ * C_;
    const unsigned short* Vbase = Vg + (size_t)b * C_ * N_;

    bf16x8 qa[2][16];
#pragma unroll
    for (int u = 0; u < 2; ++u) {
        const unsigned short* qb =
            Qt + ((size_t)b * N_ + q0 + w * 32 + u * 16 + l15) * C_ + quad * 8;
#pragma unroll
        for (int ck = 0; ck < 16; ++ck) qa[u][ck] = *(const bf16x8*)(qb + ck * 32);
    }

    f32x4 o[2][32] = {};
    float lrow[2][4] = {};

    {
        int k0 = kbeg;
#pragma unroll
        for (int i = 0; i < 8; ++i) {
            int r = w * 8 + i;
            async16(Kbase + (size_t)(k0 + r) * C_ + ((lane ^ (r & 7)) * 8), Kl + r * 512);
        }
#pragma unroll
        for (int i = 0; i < 8; ++i) {
            int idx = w * 8 + i, kc = idx >> 3, cb = idx & 7;
            async16(Vbase + (size_t)(cb * 64 + lane) * N_ + k0 + kc * 8,
                    Vl + (kc * 512 + cb * 64) * 8);
        }
    }

    for (int kt = 0; kt < nkt; ++kt) {
        int cur = kt & 1, nxt = cur ^ 1;
        __builtin_amdgcn_s_waitcnt(0x3F70);
        __syncthreads();
        if (kt + 1 < nkt) {
            int k0 = kbeg + (kt + 1) * 32;
#pragma unroll
            for (int i = 0; i < 8; ++i) {
                int r = w * 8 + i;
                async16(Kbase + (size_t)(k0 + r) * C_ + ((lane ^ (r & 7)) * 8),
                        Kl + nxt * 16384 + r * 512);
            }
#pragma unroll
            for (int i = 0; i < 8; ++i) {
                int idx = w * 8 + i, kc = idx >> 3, cb = idx & 7;
                async16(Vbase + (size_t)(cb * 64 + lane) * N_ + k0 + kc * 8,
                        Vl + nxt * 16384 + (kc * 512 + cb * 64) * 8);
            }
        }
        const unsigned short* Kc = Kl + cur * 16384;
        f32x4 s00 = {}, s01 = {}, s10 = {}, s11 = {};
#pragma unroll
        for (int ck = 0; ck < 16; ++ck) {
            int slot = (ck * 4 + quad) ^ xr;
            bf16x8 b0 = *(const bf16x8*)&Kc[l15 * 512 + slot * 8];
            bf16x8 b1 = *(const bf16x8*)&Kc[(16 + l15) * 512 + slot * 8];
            s00 = MFMA16(qa[0][ck], b0, s00);
            s10 = MFMA16(qa[1][ck], b0, s10);
            s01 = MFMA16(qa[0][ck], b1, s01);
            s11 = MFMA16(qa[1][ck], b1, s11);
        }
        unsigned short* pb = &Pl[w * 1152];
#pragma unroll
        for (int r = 0; r < 4; ++r) {
            float p00 = __expf(s00[r] * SCALE - ESHIFT);
            float p01 = __expf(s01[r] * SCALE - ESHIFT);
            float p10 = __expf(s10[r] * SCALE - ESHIFT);
            float p11 = __expf(s11[r] * SCALE - ESHIFT);
            lrow[0][r] += p00 + p01;
            lrow[1][r] += p10 + p11;
            int row0 = (quad * 4 + r) * 36;
            int row1 = (16 + quad * 4 + r) * 36;
            pb[row0 + l15]      = f2bf(p00);
            pb[row0 + 16 + l15] = f2bf(p01);
            pb[row1 + l15]      = f2bf(p10);
            pb[row1 + 16 + l15] = f2bf(p11);
        }
        __builtin_amdgcn_s_waitcnt(0xC07F);
        bf16x8 pa0 = *(const bf16x8*)&Pl[w * 1152 + l15 * 36 + quad * 8];
        bf16x8 pa1 = *(const bf16x8*)&Pl[w * 1152 + (16 + l15) * 36 + quad * 8];
        const unsigned short* Vc = Vl + cur * 16384;
#pragma unroll
        for (int cf = 0; cf < 32; ++cf) {
            bf16x8 vb = *(const bf16x8*)&Vc[(quad * 512 + cf * 16 + l15) * 8];
            o[0][cf] = MFMA16(pa0, vb, o[0][cf]);
            o[1][cf] = MFMA16(pa1, vb, o[1][cf]);
        }
    }
#pragma unroll
    for (int u = 0; u < 2; ++u)
#pragma unroll
        for (int r = 0; r < 4; ++r) {
            float l = lrow[u][r];
            l += __shfl_xor(l, 1);
            l += __shfl_xor(l, 2);
            l += __shfl_xor(l, 4);
            l += __shfl_xor(l, 8);
            lrow[u][r] = l;
        }
    size_t pbase = (size_t)(s * B_ + b) * N_;
#pragma unroll
    for (int u = 0; u < 2; ++u)
#pragma unroll
        for (int cf = 0; cf < 32; ++cf)
#pragma unroll
            for (int r = 0; r < 4; ++r) {
                int q = q0 + w * 32 + u * 16 + quad * 4 + r;
                part[(pbase + q) * C_ + cf * 16 + l15] = f2bf(o[u][cf][r]);
            }
    if (l15 == 0) {
#pragma unroll
        for (int u = 0; u < 2; ++u)
#pragma unroll
            for (int r = 0; r < 4; ++r) {
                int q = q0 + w * 32 + u * 16 + quad * 4 + r;
                lbuf[pbase + q] = lrow[u][r];
            }
    }
}

__global__ __launch_bounds__(256) void attn_combine(const unsigned short* __restrict__ part,
                                                    const float* __restrict__ lbuf,
                                                    unsigned short* __restrict__ ao,
                                                    int nsplit) {
    size_t idx = (size_t)blockIdx.x * 256 + threadIdx.x;
    int cu = (int)(idx & 63);
    size_t row = idx >> 6;
    float l = lbuf[row];
    union { uint4 v; unsigned short u[8]; } p1, p2, outv;
    p1.v = *(const uint4*)&part[row * C_ + cu * 8];
    if (nsplit == 2) {
        l += lbuf[(size_t)B_ * N_ + row];
        p2.v = *(const uint4*)&part[((size_t)B_ * N_ + row) * C_ + cu * 8];
    } else {
        p2.v = make_uint4(0, 0, 0, 0);
    }
    float inv = 1.f / l;
#pragma unroll
    for (int j = 0; j < 8; ++j)
        outv.u[j] = f2bf((bf2f(p1.u[j]) + bf2f(p2.u[j])) * inv);
    *(uint4*)&ao[row * C_ + cu * 8] = outv.v;
}

// ---------------------------------------------------------------------------
extern "C" void kernel_launch(void* const* d_in, const int* in_sizes, int n_in,
                              void* d_out, int out_size, void* d_ws, size_t ws_size,
                              hipStream_t stream) {
    const float* x   = (const float*)d_in[0];
    const float* gam = (const float*)d_in[1];
    const float* bet = (const float*)d_in[2];
    const float* wq  = (const float*)d_in[3];
    const float* bq  = (const float*)d_in[4];
    const float* wk  = (const float*)d_in[5];
    const float* bk  = (const float*)d_in[6];
    const float* wv  = (const float*)d_in[7];
    const float* bv  = (const float*)d_in[8];
    const float* wo  = (const float*)d_in[9];
    const float* bo  = (const float*)d_in[10];
    float* out = (float*)d_out;

    char* ws = (char*)d_ws;
    const size_t SZH = (size_t)B_ * N_ * C_ * 2;          // 16 MiB bf16 tensor
    const size_t OFF_HT = 4096;
    const size_t OFF_QT = OFF_HT + SZH;
    const size_t OFF_KT = OFF_QT + SZH;
    const size_t OFF_VG = OFF_KT + SZH;
    const size_t OFF_WB = OFF_VG + SZH;
    const size_t OFF_X  = OFF_WB + 2097152;               // 69,210,112
    float*          stats = (float*)ws;
    unsigned short* Ht    = (unsigned short*)(ws + OFF_HT);
    unsigned short* Qt    = (unsigned short*)(ws + OFF_QT);
    unsigned short* Kt    = (unsigned short*)(ws + OFF_KT);
    unsigned short* Vg    = (unsigned short*)(ws + OFF_VG);
    unsigned short* Wb    = (unsigned short*)(ws + OFF_WB);
    unsigned short* AObf  = Ht;  // Ht dead after projections

    // Path A: materialized-P two-GEMM attention.
    const size_t SZPSUM = 64ull * 16384 * 4;              // 4 MiB
    const size_t SZP    = (size_t)B_ * N_ * N_ * 2;       // 128 MiB
    float*          psum = (float*)(ws + OFF_X);
    unsigned short* P    = (unsigned short*)(ws + OFF_X + SZPSUM);
    size_t needA = OFF_X + SZPSUM + SZP;

    // Path B (fallback): R4 flash.
    float*          lbuf = (float*)(ws + OFF_X);
    unsigned short* part = (unsigned short*)(ws + OFF_X + 262144);
    size_t needB2 = OFF_X + 262144 + 2 * SZH;

    gn_stats<<<128, 256, 0, stream>>>(x, stats);
    gn_apply<<<dim3(64, 8, B_), 256, 0, stream>>>(x, gam, bet, stats, Ht);
    wconv<<<4096, 256, 0, stream>>>(wq, wk, wv, wo, Wb);
    gemm_qkv<<<dim3(32, 12, B_), 256, 0, stream>>>(Ht, Wb, bq, bk, bv, Qt, Kt, Vg);

    if (ws_size >= needA) {
        gemm_qk_exp<<<dim3(32, 32, B_), 256, 0, stream>>>(Qt, Kt, P, psum);
        gemm_pv<<<512, 256, 0, stream>>>(P, Vg, psum, AObf);
    } else {
        int nsplit = (ws_size >= needB2) ? 2 : 1;
        const int FLASH_LDS = 140288;
        (void)hipFuncSetAttribute((const void*)flash_attn,
                                  hipFuncAttributeMaxDynamicSharedMemorySize, FLASH_LDS);
        flash_attn<<<dim3(32 * B_ * nsplit), 256, FLASH_LDS, stream>>>(Qt, Kt, Vg, part, lbuf, nsplit);
        attn_combine<<<4096, 256, 0, stream>>>(part, lbuf, AObf, nsplit);
    }
    gemm_resid<<<dim3(32, 4, B_), 256, 0, stream>>>(AObf, Wb + 786432, bo, x, out);
}